// Round 11
// baseline (695.570 us; speedup 1.0000x reference)
//
#include <hip/hip_runtime.h>
#include <hip/hip_cooperative_groups.h>

namespace cg = cooperative_groups;

#define N_NODES 50000
#define N_EDGES 800000
#define EP_EDGES (N_EDGES + N_NODES)
#define N_GRAPHS 256
#define COOP_BLOCKS 256

typedef unsigned short u16;
typedef __attribute__((ext_vector_type(8))) short s8v;    // 8 x bf16 (4 VGPRs)
typedef __attribute__((ext_vector_type(4))) float f4v;    // mfma accumulator

// ---------- bf16 helpers (RNE) ----------
__device__ __forceinline__ u16 fb(float f) {
  unsigned u = __float_as_uint(f);
  return (u16)((u + 0x7fffu + ((u >> 16) & 1u)) >> 16);
}
__device__ __forceinline__ float bfl(unsigned p) {
  return __uint_as_float(p << 16);
}
__device__ __forceinline__ float bfh(unsigned p) {
  return __uint_as_float(p & 0xffff0000u);
}
__device__ __forceinline__ float bff(u16 s) {
  return __uint_as_float(((unsigned)s) << 16);
}

#define W_N1 32768
#define W_N2 (W_N1 + 65536)
#define W_N3 (W_N2 + 16384)

// ---------- cooperative prep: zero + weight-convert + hist + scan + scatter --
__global__ __launch_bounds__(256) void prep_coop(
    const int* __restrict__ ei, int* __restrict__ deg, int* __restrict__ fill,
    int* __restrict__ rowstart, int* __restrict__ bsum, int* __restrict__ boff,
    int* __restrict__ esrc, const float* __restrict__ w1,
    const float* __restrict__ w2, const float* __restrict__ w3,
    u16* __restrict__ w1b, u16* __restrict__ w2b, u16* __restrict__ w3b) {
  cg::grid_group grid = cg::this_grid();
  const int tid = blockIdx.x * 256 + threadIdx.x;
  const int nthr = COOP_BLOCKS * 256;  // 65536 >= N_NODES
  __shared__ int sh[256];

  // phase 0: zero deg+fill (adjacent), convert weights to bf16
  for (int i = tid; i < 2 * N_NODES; i += nthr) deg[i] = 0;
  for (int i = tid; i < W_N3; i += nthr) {
    if (i < W_N1) w1b[i] = fb(w1[i]);
    else if (i < W_N2) w2b[i - W_N1] = fb(w2[i - W_N1]);
    else w3b[i - W_N2] = fb(w3[i - W_N2]);
  }
  grid.sync();
  // phase 1: degree histogram
  for (int e = tid; e < EP_EDGES; e += nthr) {
    int d = (e < N_EDGES) ? ei[N_EDGES + e] : e - N_EDGES;
    atomicAdd(&deg[d], 1);
  }
  grid.sync();
  // phase 2: block-local exclusive scan (thread tid <-> element tid)
  {
    int v = (tid < N_NODES) ? deg[tid] : 0;
    sh[threadIdx.x] = v;
    __syncthreads();
    for (int off = 1; off < 256; off <<= 1) {
      int add = (threadIdx.x >= off) ? sh[threadIdx.x - off] : 0;
      __syncthreads();
      sh[threadIdx.x] += add;
      __syncthreads();
    }
    if (tid < N_NODES) rowstart[tid] = sh[threadIdx.x] - v;
    if (threadIdx.x == 255) bsum[blockIdx.x] = sh[255];
  }
  grid.sync();
  // phase 3: scan block sums (block 0 only; COOP_BLOCKS == 256)
  if (blockIdx.x == 0) {
    int v = bsum[threadIdx.x];
    sh[threadIdx.x] = v;
    __syncthreads();
    for (int off = 1; off < 256; off <<= 1) {
      int add = (threadIdx.x >= off) ? sh[threadIdx.x - off] : 0;
      __syncthreads();
      sh[threadIdx.x] += add;
      __syncthreads();
    }
    boff[threadIdx.x] = sh[threadIdx.x] - v;
  }
  grid.sync();
  // phase 4: add block offsets
  for (int i = tid; i < N_NODES; i += nthr) rowstart[i] += boff[i >> 8];
  if (tid == 0) rowstart[N_NODES] = EP_EDGES;
  grid.sync();
  // phase 5: scatter src ids into CSR order
  for (int e = tid; e < EP_EDGES; e += nthr) {
    int s, d;
    if (e < N_EDGES) { s = ei[e]; d = ei[N_EDGES + e]; }
    else             { s = d = e - N_EDGES; }
    int pos = rowstart[d] + atomicAdd(&fill[d], 1);
    esrc[pos] = s;
  }
}

// ---------- fused attn-score epilogue (gemm128 family, H=4) ----------
__device__ __forceinline__ void score_epilogue(
    f4v (&acc)[4][4], const float* __restrict__ a_src,
    const float* __restrict__ a_dst, float* __restrict__ alo,
    float* __restrict__ ahi, int m0, int n0, int wi, int wj, int quad, int fr,
    int M) {
  const int head = (n0 + wj) >> 6;
  float as[4], ad[4];
#pragma unroll
  for (int j = 0; j < 4; ++j) {
    int col = n0 + wj + j * 16 + fr;
    as[j] = a_src[col];
    ad[j] = a_dst[col];
  }
#pragma unroll
  for (int i = 0; i < 4; ++i) {
#pragma unroll
    for (int r = 0; r < 4; ++r) {
      float s = 0.f, d = 0.f;
#pragma unroll
      for (int j = 0; j < 4; ++j) {
        s += acc[i][j][r] * as[j];
        d += acc[i][j][r] * ad[j];
      }
#pragma unroll
      for (int off = 8; off; off >>= 1) {
        s += __shfl_xor(s, off, 64);
        d += __shfl_xor(d, off, 64);
      }
      int row = m0 + wi + i * 16 + quad * 4 + r;
      if (fr == 0 && row < M) {
        alo[row * 4 + head] = s;
        ahi[row * 4 + head] = d;
      }
    }
  }
}

// ---------- 128x128-tile bf16 GEMM + fused scores (layer 2) ----------
__global__ __launch_bounds__(256) void gemm128(
    const u16* __restrict__ A, const u16* __restrict__ W,
    u16* __restrict__ C, const float* __restrict__ a_src,
    const float* __restrict__ a_dst, float* __restrict__ alo,
    float* __restrict__ ahi, int M, int Nout, int K) {
  __shared__ u16 As[128][40];
  __shared__ u16 Bs[128][40];
  const int t = threadIdx.x;
  const int m0 = blockIdx.y * 128, n0 = blockIdx.x * 128;
  const int rq = t >> 2, q = t & 3;
  const int w = t >> 6, lane = t & 63;
  const int wi = (w & 1) * 64, wj = (w >> 1) * 64;
  const int quad = lane >> 4, fr = lane & 15;

  f4v acc[4][4] = {};
  for (int k0 = 0; k0 < K; k0 += 32) {
    uint4 av[2], bv[2];
#pragma unroll
    for (int g = 0; g < 2; ++g) {
      int r = rq + g * 64;
      int m = m0 + r;
      av[g] = (m < M) ? *(const uint4*)&A[(size_t)m * K + k0 + q * 8]
                      : make_uint4(0, 0, 0, 0);
      bv[g] = *(const uint4*)&W[(size_t)(n0 + r) * K + k0 + q * 8];
    }
    __syncthreads();
#pragma unroll
    for (int g = 0; g < 2; ++g) {
      *(uint4*)&As[rq + g * 64][q * 8] = av[g];
      *(uint4*)&Bs[rq + g * 64][q * 8] = bv[g];
    }
    __syncthreads();
    s8v af[4], bf_[4];
#pragma unroll
    for (int i = 0; i < 4; ++i) {
      af[i] = *(const s8v*)&As[wi + i * 16 + fr][quad * 8];
      bf_[i] = *(const s8v*)&Bs[wj + i * 16 + fr][quad * 8];
    }
#pragma unroll
    for (int i = 0; i < 4; ++i)
#pragma unroll
      for (int j = 0; j < 4; ++j)
        acc[i][j] =
            __builtin_amdgcn_mfma_f32_16x16x32_bf16(af[i], bf_[j], acc[i][j], 0, 0, 0);
  }
#pragma unroll
  for (int i = 0; i < 4; ++i) {
    int rbase = m0 + wi + i * 16 + quad * 4;
#pragma unroll
    for (int j = 0; j < 4; ++j) {
      int col = n0 + wj + j * 16 + fr;
#pragma unroll
      for (int r = 0; r < 4; ++r) {
        int row = rbase + r;
        if (row < M) C[(size_t)row * Nout + col] = fb(acc[i][j][r]);
      }
    }
  }
  score_epilogue(acc, a_src, a_dst, alo, ahi, m0, n0, wi, wj, quad, fr, M);
}

// ---------- 128x128-tile GEMM, f32 A input + fused scores (layer 1) ----------
__global__ __launch_bounds__(256) void gemm128_f32(
    const float* __restrict__ A, const u16* __restrict__ W,
    u16* __restrict__ C, const float* __restrict__ a_src,
    const float* __restrict__ a_dst, float* __restrict__ alo,
    float* __restrict__ ahi, int M, int Nout, int K) {
  __shared__ u16 As[128][40];
  __shared__ u16 Bs[128][40];
  const int t = threadIdx.x;
  const int m0 = blockIdx.y * 128, n0 = blockIdx.x * 128;
  const int rq = t >> 2, q = t & 3;
  const int w = t >> 6, lane = t & 63;
  const int wi = (w & 1) * 64, wj = (w >> 1) * 64;
  const int quad = lane >> 4, fr = lane & 15;

  f4v acc[4][4] = {};
  for (int k0 = 0; k0 < K; k0 += 32) {
    uint4 av[2], bv[2];
#pragma unroll
    for (int g = 0; g < 2; ++g) {
      int r = rq + g * 64;
      int m = m0 + r;
      if (m < M) {
        float4 f0 = *(const float4*)&A[(size_t)m * K + k0 + q * 8];
        float4 f1 = *(const float4*)&A[(size_t)m * K + k0 + q * 8 + 4];
        av[g].x = (unsigned)fb(f0.x) | ((unsigned)fb(f0.y) << 16);
        av[g].y = (unsigned)fb(f0.z) | ((unsigned)fb(f0.w) << 16);
        av[g].z = (unsigned)fb(f1.x) | ((unsigned)fb(f1.y) << 16);
        av[g].w = (unsigned)fb(f1.z) | ((unsigned)fb(f1.w) << 16);
      } else {
        av[g] = make_uint4(0, 0, 0, 0);
      }
      bv[g] = *(const uint4*)&W[(size_t)(n0 + r) * K + k0 + q * 8];
    }
    __syncthreads();
#pragma unroll
    for (int g = 0; g < 2; ++g) {
      *(uint4*)&As[rq + g * 64][q * 8] = av[g];
      *(uint4*)&Bs[rq + g * 64][q * 8] = bv[g];
    }
    __syncthreads();
    s8v af[4], bf_[4];
#pragma unroll
    for (int i = 0; i < 4; ++i) {
      af[i] = *(const s8v*)&As[wi + i * 16 + fr][quad * 8];
      bf_[i] = *(const s8v*)&Bs[wj + i * 16 + fr][quad * 8];
    }
#pragma unroll
    for (int i = 0; i < 4; ++i)
#pragma unroll
      for (int j = 0; j < 4; ++j)
        acc[i][j] =
            __builtin_amdgcn_mfma_f32_16x16x32_bf16(af[i], bf_[j], acc[i][j], 0, 0, 0);
  }
#pragma unroll
  for (int i = 0; i < 4; ++i) {
    int rbase = m0 + wi + i * 16 + quad * 4;
#pragma unroll
    for (int j = 0; j < 4; ++j) {
      int col = n0 + wj + j * 16 + fr;
#pragma unroll
      for (int r = 0; r < 4; ++r) {
        int row = rbase + r;
        if (row < M) C[(size_t)row * Nout + col] = fb(acc[i][j][r]);
      }
    }
  }
  score_epilogue(acc, a_src, a_dst, alo, ahi, m0, n0, wi, wj, quad, fr, M);
}

// ---------- 64x64-tile GEMM + fused H=1 scores (layer 3, Nout=64) ----------
__global__ __launch_bounds__(256) void gemm64_s(
    const u16* __restrict__ A, const u16* __restrict__ W,
    u16* __restrict__ C, const float* __restrict__ a_src,
    const float* __restrict__ a_dst, float* __restrict__ alo,
    float* __restrict__ ahi, int M, int Nout, int K) {
  __shared__ u16 As[64][40];
  __shared__ u16 Bs[64][40];
  __shared__ float sh_s[64][2], sh_d[64][2];
  const int t = threadIdx.x;
  const int m0 = blockIdx.y * 64, n0 = blockIdx.x * 64;
  const int r = t >> 2, c = t & 3;
  const int w = t >> 6, lane = t & 63;
  const int mi = (w & 1) * 32, ni = (w >> 1) * 32;
  const int quad = lane >> 4, fr = lane & 15;

  f4v c00{}, c01{}, c10{}, c11{};
  for (int k0 = 0; k0 < K; k0 += 32) {
    uint4 av = make_uint4(0, 0, 0, 0);
    int m = m0 + r;
    if (m < M) av = *(const uint4*)&A[(size_t)m * K + k0 + c * 8];
    uint4 bv = *(const uint4*)&W[(size_t)(n0 + r) * K + k0 + c * 8];
    __syncthreads();
    *(uint4*)&As[r][c * 8] = av;
    *(uint4*)&Bs[r][c * 8] = bv;
    __syncthreads();
    s8v a0 = *(const s8v*)&As[mi + fr][quad * 8];
    s8v a1 = *(const s8v*)&As[mi + 16 + fr][quad * 8];
    s8v b0 = *(const s8v*)&Bs[ni + fr][quad * 8];
    s8v b1 = *(const s8v*)&Bs[ni + 16 + fr][quad * 8];
    c00 = __builtin_amdgcn_mfma_f32_16x16x32_bf16(a0, b0, c00, 0, 0, 0);
    c01 = __builtin_amdgcn_mfma_f32_16x16x32_bf16(a0, b1, c01, 0, 0, 0);
    c10 = __builtin_amdgcn_mfma_f32_16x16x32_bf16(a1, b0, c10, 0, 0, 0);
    c11 = __builtin_amdgcn_mfma_f32_16x16x32_bf16(a1, b1, c11, 0, 0, 0);
  }
  const int col = n0 + ni + fr;
#pragma unroll
  for (int i = 0; i < 4; ++i) {
    int row = m0 + mi + quad * 4 + i;
    if (row < M) {
      C[(size_t)row * Nout + col] = fb(c00[i]);
      C[(size_t)row * Nout + col + 16] = fb(c01[i]);
    }
    int row2 = row + 16;
    if (row2 < M) {
      C[(size_t)row2 * Nout + col] = fb(c10[i]);
      C[(size_t)row2 * Nout + col + 16] = fb(c11[i]);
    }
  }
  // fused H=1 scores: wave covers rows [mi,mi+32), cols [ni,ni+32)
  const float as_lo = a_src[ni + fr], as_hi = a_src[ni + 16 + fr];
  const float ad_lo = a_dst[ni + fr], ad_hi = a_dst[ni + 16 + fr];
#pragma unroll
  for (int i = 0; i < 4; ++i) {
    float s0 = c00[i] * as_lo + c01[i] * as_hi;
    float d0 = c00[i] * ad_lo + c01[i] * ad_hi;
    float s1 = c10[i] * as_lo + c11[i] * as_hi;
    float d1 = c10[i] * ad_lo + c11[i] * ad_hi;
#pragma unroll
    for (int off = 8; off; off >>= 1) {
      s0 += __shfl_xor(s0, off, 64);
      d0 += __shfl_xor(d0, off, 64);
      s1 += __shfl_xor(s1, off, 64);
      d1 += __shfl_xor(d1, off, 64);
    }
    if (fr == 0) {
      sh_s[mi + quad * 4 + i][ni >> 5] = s0;
      sh_d[mi + quad * 4 + i][ni >> 5] = d0;
      sh_s[mi + 16 + quad * 4 + i][ni >> 5] = s1;
      sh_d[mi + 16 + quad * 4 + i][ni >> 5] = d1;
    }
  }
  __syncthreads();
  if (t < 64) {
    int row = m0 + t;
    if (row < M) {
      alo[row] = sh_s[t][0] + sh_s[t][1];
      ahi[row] = sh_d[t][0] + sh_d[t][1];
    }
  }
}

// ---------- aggregation H=4: single-pass softmax, no cross-lane ops ----
__global__ __launch_bounds__(64) void agg4(
    const int* __restrict__ rowstart, const int* __restrict__ esrc,
    const u16* __restrict__ hbuf, const float* __restrict__ alo,
    const float* __restrict__ ahi, const float* __restrict__ bias,
    u16* __restrict__ feat) {
  const int d = blockIdx.x;
  const int lane = threadIdx.x;
  const int head = lane >> 4;
  const int c = lane * 4;
  const int s0 = rowstart[d], s1 = rowstart[d + 1];
  const float ah = ahi[d * 4 + head];

  float l = 0.f, o0 = 0.f, o1 = 0.f, o2 = 0.f, o3 = 0.f;
  for (int j = s0; j < s1; j += 8) {
    int ss[8];
    float wq[8];
#pragma unroll
    for (int q = 0; q < 8; ++q) {
      int jj = j + q;
      int sv = esrc[jj < EP_EDGES ? jj : EP_EDGES - 1];
      ss[q] = (jj < s1) ? sv : d;
    }
#pragma unroll
    for (int q = 0; q < 8; ++q) {
      float e = alo[ss[q] * 4 + head] + ah;
      e = e > 0.f ? e : 0.2f * e;
      wq[q] = (j + q < s1) ? __expf(e) : 0.f;
    }
    uint2 hv[8];
#pragma unroll
    for (int q = 0; q < 8; ++q)
      hv[q] = *(const uint2*)&hbuf[(size_t)ss[q] * 256 + c];
#pragma unroll
    for (int q = 0; q < 8; ++q) {
      l += wq[q];
      o0 += wq[q] * bfl(hv[q].x);
      o1 += wq[q] * bfh(hv[q].x);
      o2 += wq[q] * bfl(hv[q].y);
      o3 += wq[q] * bfh(hv[q].y);
    }
  }
  const float inv = 1.f / (l + 1e-16f);
  float4 bv = *(const float4*)&bias[c];
  float v0 = o0 * inv + bv.x, v1 = o1 * inv + bv.y;
  float v2 = o2 * inv + bv.z, v3 = o3 * inv + bv.w;
  v0 = v0 > 0.f ? v0 : __expf(v0) - 1.f;
  v1 = v1 > 0.f ? v1 : __expf(v1) - 1.f;
  v2 = v2 > 0.f ? v2 : __expf(v2) - 1.f;
  v3 = v3 > 0.f ? v3 : __expf(v3) - 1.f;
  uint2 pv;
  pv.x = (unsigned)fb(v0) | ((unsigned)fb(v1) << 16);
  pv.y = (unsigned)fb(v2) | ((unsigned)fb(v3) << 16);
  *(uint2*)&feat[(size_t)d * 256 + c] = pv;
}

// ---------- aggregation H=1: single-pass, precomputed alo/ahi ----------
__global__ __launch_bounds__(64) void agg1(
    const int* __restrict__ rowstart, const int* __restrict__ esrc,
    const u16* __restrict__ hbuf, const float* __restrict__ alo,
    const float* __restrict__ ahi, const float* __restrict__ bias,
    float* __restrict__ feat) {
  const int d = blockIdx.x;
  const int t = threadIdx.x;
  const int s0 = rowstart[d], s1 = rowstart[d + 1];
  const float ah = ahi[d];

  float l = 0.f, o = 0.f;
  for (int j = s0; j < s1; j += 4) {
    int ss[4];
    float wq[4];
#pragma unroll
    for (int q = 0; q < 4; ++q) {
      int jj = j + q;
      int sv = esrc[jj < EP_EDGES ? jj : EP_EDGES - 1];
      ss[q] = (jj < s1) ? sv : d;
    }
#pragma unroll
    for (int q = 0; q < 4; ++q) {
      float e = alo[ss[q]] + ah;
      e = e > 0.f ? e : 0.2f * e;
      wq[q] = (j + q < s1) ? __expf(e) : 0.f;
    }
    u16 hv[4];
#pragma unroll
    for (int q = 0; q < 4; ++q) hv[q] = hbuf[(size_t)ss[q] * 64 + t];
#pragma unroll
    for (int q = 0; q < 4; ++q) {
      l += wq[q];
      o += wq[q] * bff(hv[q]);
    }
  }
  float v = o / (l + 1e-16f) + bias[t];
  feat[(size_t)d * 64 + t] = v > 0.f ? v : __expf(v) - 1.f;
}

// ---------- fused mean-pool + MLP heads: one block per graph ----------
__global__ __launch_bounds__(64) void poolheads(
    const float* __restrict__ feat, const int* __restrict__ batch,
    const float* __restrict__ Wc1, const float* __restrict__ bc1,
    const float* __restrict__ Wc2, const float* __restrict__ bc2,
    const float* __restrict__ Wr1, const float* __restrict__ br1,
    const float* __restrict__ Wr2, const float* __restrict__ br2,
    float* __restrict__ out) {
  const int gi = blockIdx.x, t = threadIdx.x;
  int l = 0, r = N_NODES;
  while (l < r) { int m = (l + r) >> 1; if (batch[m] < gi) l = m + 1; else r = m; }
  const int lo = l;
  r = N_NODES;
  while (l < r) { int m = (l + r) >> 1; if (batch[m] < gi + 1) l = m + 1; else r = m; }
  const int hi = l;

  float acc = 0.f;
  for (int n = lo; n < hi; ++n) acc += feat[(size_t)n * 64 + t];
  float cnt = (float)(hi - lo);
  cnt = cnt < 1.f ? 1.f : cnt;

  __shared__ float g[64];
  g[t] = acc / cnt;
  __syncthreads();
  float hc = bc1[t], hr = br1[t];
#pragma unroll 8
  for (int c = 0; c < 64; ++c) {
    float gv = g[c];
    hc += gv * Wc1[t * 64 + c];
    hr += gv * Wr1[t * 64 + c];
  }
  hc = fmaxf(hc, 0.f) * Wc2[t];
  hr = fmaxf(hr, 0.f) * Wr2[t];
#pragma unroll
  for (int off = 32; off; off >>= 1) {
    hc += __shfl_down(hc, off, 64);
    hr += __shfl_down(hr, off, 64);
  }
  if (t == 0) {
    out[gi] = hc + bc2[0];
    out[N_GRAPHS + gi] = hr + br2[0];
  }
}

extern "C" void kernel_launch(void* const* d_in, const int* in_sizes, int n_in,
                              void* d_out, int out_size, void* d_ws,
                              size_t ws_size, hipStream_t stream) {
  const float* x   = (const float*)d_in[0];
  const int* ei    = (const int*)d_in[1];
  const int* batch = (const int*)d_in[2];
  const float* W1  = (const float*)d_in[3];
  const float* as1 = (const float*)d_in[4];
  const float* ad1 = (const float*)d_in[5];
  const float* b1  = (const float*)d_in[6];
  const float* W2  = (const float*)d_in[7];
  const float* as2 = (const float*)d_in[8];
  const float* ad2 = (const float*)d_in[9];
  const float* b2  = (const float*)d_in[10];
  const float* W3  = (const float*)d_in[11];
  const float* as3 = (const float*)d_in[12];
  const float* ad3 = (const float*)d_in[13];
  const float* b3  = (const float*)d_in[14];
  const float* Wc1 = (const float*)d_in[15];
  const float* bc1 = (const float*)d_in[16];
  const float* Wc2 = (const float*)d_in[17];
  const float* bc2 = (const float*)d_in[18];
  const float* Wr1 = (const float*)d_in[19];
  const float* br1 = (const float*)d_in[20];
  const float* Wr2 = (const float*)d_in[21];
  const float* br2 = (const float*)d_in[22];
  float* out = (float*)d_out;

  // ---- workspace layout ----
  float* ws = (float*)d_ws;
  u16* h_buf = (u16*)ws;
  float* p = ws + (size_t)N_NODES * 128;
  u16* featb = (u16*)p;
  p += (size_t)N_NODES * 128;
  u16* W1b = (u16*)p; p += 16384;
  u16* W2b = (u16*)p; p += 32768;
  u16* W3b = (u16*)p; p += 8192;
  float* feat3 = p;   p += (size_t)N_NODES * 64;
  float* alo   = p;   p += (size_t)N_NODES * 4;
  float* ahi   = p;   p += (size_t)N_NODES * 4;
  int* rowstart = (int*)p; p += (N_NODES + 4);
  int* esrc    = (int*)p;  p += EP_EDGES;
  float* bsc   = p;
  int* deg  = (int*)alo;                // [N] (clobbered before alo is written)
  int* fill = (int*)alo + N_NODES;      // [N] adjacent
  int* bsum = (int*)bsc;                // [256]
  int* boff = (int*)bsc + 256;          // [256]

  // ---- cooperative prep: zero + f2b weights + hist + scan + scatter ----
  {
    void* args[] = {(void*)&ei,  (void*)&deg,  (void*)&fill, (void*)&rowstart,
                    (void*)&bsum, (void*)&boff, (void*)&esrc, (void*)&W1,
                    (void*)&W2,   (void*)&W3,   (void*)&W1b,  (void*)&W2b,
                    (void*)&W3b};
    hipLaunchCooperativeKernel((const void*)prep_coop, dim3(COOP_BLOCKS),
                               dim3(256), args, 0, stream);
  }

  const int MB128 = (N_NODES + 127) / 128;
  const int MB64 = (N_NODES + 63) / 64;
  // ---- layer 1 (f32 x input; scores fused) ----
  gemm128_f32<<<dim3(2, MB128), 256, 0, stream>>>(x, W1b, h_buf, as1, ad1, alo,
                                                  ahi, N_NODES, 256, 128);
  agg4<<<N_NODES, 64, 0, stream>>>(rowstart, esrc, h_buf, alo, ahi, b1, featb);
  // ---- layer 2 (scores fused) ----
  gemm128<<<dim3(2, MB128), 256, 0, stream>>>(featb, W2b, h_buf, as2, ad2, alo,
                                              ahi, N_NODES, 256, 256);
  agg4<<<N_NODES, 64, 0, stream>>>(rowstart, esrc, h_buf, alo, ahi, b2, featb);
  // ---- layer 3 (scores fused in gemm64_s epilogue) ----
  gemm64_s<<<dim3(1, MB64), 256, 0, stream>>>(featb, W3b, h_buf, as3, ad3, alo,
                                              ahi, N_NODES, 64, 256);
  agg1<<<N_NODES, 64, 0, stream>>>(rowstart, esrc, h_buf, alo, ahi, b3, feat3);

  // ---- fused mean pool + heads ----
  poolheads<<<N_GRAPHS, 64, 0, stream>>>(feat3, batch, Wc1, bc1, Wc2, bc2, Wr1,
                                         br1, Wr2, br2, out);
}

// Round 12
// 540.724 us; speedup vs baseline: 1.2864x; 1.2864x over previous
//
#include <hip/hip_runtime.h>

#define N_NODES 50000
#define N_EDGES 800000
#define EP_EDGES (N_EDGES + N_NODES)
#define N_GRAPHS 256
#define NBLK_SCAN ((N_NODES + 255) / 256)

typedef unsigned short u16;
typedef __attribute__((ext_vector_type(8))) short s8v;    // 8 x bf16 (4 VGPRs)
typedef __attribute__((ext_vector_type(4))) float f4v;    // mfma accumulator

// ---------- bf16 helpers (RNE) ----------
__device__ __forceinline__ u16 fb(float f) {
  unsigned u = __float_as_uint(f);
  return (u16)((u + 0x7fffu + ((u >> 16) & 1u)) >> 16);
}
__device__ __forceinline__ float bfl(unsigned p) {
  return __uint_as_float(p << 16);
}
__device__ __forceinline__ float bfh(unsigned p) {
  return __uint_as_float(p & 0xffff0000u);
}
__device__ __forceinline__ float bff(u16 s) {
  return __uint_as_float(((unsigned)s) << 16);
}

// ---------- f32->bf16 conversion of W1, W2, W3 (weights only) ----------
#define W_N1 32768
#define W_N2 (W_N1 + 65536)
#define W_N3 (W_N2 + 16384)
__global__ void f2bw(const float* __restrict__ w1, const float* __restrict__ w2,
                     const float* __restrict__ w3, u16* __restrict__ w1b,
                     u16* __restrict__ w2b, u16* __restrict__ w3b) {
  int i = blockIdx.x * 256 + threadIdx.x;
  if (i < W_N1) w1b[i] = fb(w1[i]);
  else if (i < W_N2) w2b[i - W_N1] = fb(w2[i - W_N1]);
  else if (i < W_N3) w3b[i - W_N2] = fb(w3[i - W_N2]);
}

// ---------- CSR build (separate kernels: oversubscribed, fast) ----------
__global__ void k_hist(const int* __restrict__ ei, int* __restrict__ deg) {
  int e = blockIdx.x * 256 + threadIdx.x;
  if (e >= EP_EDGES) return;
  int d = (e < N_EDGES) ? ei[N_EDGES + e] : e - N_EDGES;
  atomicAdd(&deg[d], 1);
}

__global__ void k_scan_local(const int* __restrict__ deg,
                             int* __restrict__ rowstart,
                             int* __restrict__ bsum) {
  __shared__ int sh[256];
  const int tid = threadIdx.x;
  const int i = blockIdx.x * 256 + tid;
  int v = (i < N_NODES) ? deg[i] : 0;
  sh[tid] = v;
  __syncthreads();
  for (int off = 1; off < 256; off <<= 1) {
    int add = (tid >= off) ? sh[tid - off] : 0;
    __syncthreads();
    sh[tid] += add;
    __syncthreads();
  }
  if (i < N_NODES) rowstart[i] = sh[tid] - v;
  if (tid == 255) bsum[blockIdx.x] = sh[255];
}

__global__ void k_scan_bsum(int* __restrict__ bsum, int* __restrict__ boff) {
  __shared__ int sh[256];
  const int tid = threadIdx.x;
  int v = (tid < NBLK_SCAN) ? bsum[tid] : 0;
  sh[tid] = v;
  __syncthreads();
  for (int off = 1; off < 256; off <<= 1) {
    int add = (tid >= off) ? sh[tid - off] : 0;
    __syncthreads();
    sh[tid] += add;
    __syncthreads();
  }
  boff[tid] = sh[tid] - v;
}

__global__ void k_scan_add(int* __restrict__ rowstart,
                           const int* __restrict__ boff) {
  int i = blockIdx.x * 256 + threadIdx.x;
  if (i < N_NODES) rowstart[i] += boff[i >> 8];
  if (i == N_NODES) rowstart[N_NODES] = EP_EDGES;
}

__global__ void k_scatter(const int* __restrict__ ei,
                          const int* __restrict__ rowstart,
                          int* __restrict__ fill, int* __restrict__ esrc) {
  int e = blockIdx.x * 256 + threadIdx.x;
  if (e >= EP_EDGES) return;
  int s, d;
  if (e < N_EDGES) { s = ei[e]; d = ei[N_EDGES + e]; }
  else             { s = d = e - N_EDGES; }
  int pos = rowstart[d] + atomicAdd(&fill[d], 1);
  esrc[pos] = s;
}

// ---------- fused attn-score epilogue (gemm128 family, H=4) ----------
__device__ __forceinline__ void score_epilogue(
    f4v (&acc)[4][4], const float* __restrict__ a_src,
    const float* __restrict__ a_dst, float* __restrict__ alo,
    float* __restrict__ ahi, int m0, int n0, int wi, int wj, int quad, int fr,
    int M) {
  const int head = (n0 + wj) >> 6;
  float as[4], ad[4];
#pragma unroll
  for (int j = 0; j < 4; ++j) {
    int col = n0 + wj + j * 16 + fr;
    as[j] = a_src[col];
    ad[j] = a_dst[col];
  }
#pragma unroll
  for (int i = 0; i < 4; ++i) {
#pragma unroll
    for (int r = 0; r < 4; ++r) {
      float s = 0.f, d = 0.f;
#pragma unroll
      for (int j = 0; j < 4; ++j) {
        s += acc[i][j][r] * as[j];
        d += acc[i][j][r] * ad[j];
      }
#pragma unroll
      for (int off = 8; off; off >>= 1) {
        s += __shfl_xor(s, off, 64);
        d += __shfl_xor(d, off, 64);
      }
      int row = m0 + wi + i * 16 + quad * 4 + r;
      if (fr == 0 && row < M) {
        alo[row * 4 + head] = s;
        ahi[row * 4 + head] = d;
      }
    }
  }
}

// ---------- 128x128-tile bf16 GEMM + fused scores (layer 2) ----------
__global__ __launch_bounds__(256) void gemm128(
    const u16* __restrict__ A, const u16* __restrict__ W,
    u16* __restrict__ C, const float* __restrict__ a_src,
    const float* __restrict__ a_dst, float* __restrict__ alo,
    float* __restrict__ ahi, int M, int Nout, int K) {
  __shared__ u16 As[128][40];
  __shared__ u16 Bs[128][40];
  const int t = threadIdx.x;
  const int m0 = blockIdx.y * 128, n0 = blockIdx.x * 128;
  const int rq = t >> 2, q = t & 3;
  const int w = t >> 6, lane = t & 63;
  const int wi = (w & 1) * 64, wj = (w >> 1) * 64;
  const int quad = lane >> 4, fr = lane & 15;

  f4v acc[4][4] = {};
  for (int k0 = 0; k0 < K; k0 += 32) {
    uint4 av[2], bv[2];
#pragma unroll
    for (int g = 0; g < 2; ++g) {
      int r = rq + g * 64;
      int m = m0 + r;
      av[g] = (m < M) ? *(const uint4*)&A[(size_t)m * K + k0 + q * 8]
                      : make_uint4(0, 0, 0, 0);
      bv[g] = *(const uint4*)&W[(size_t)(n0 + r) * K + k0 + q * 8];
    }
    __syncthreads();
#pragma unroll
    for (int g = 0; g < 2; ++g) {
      *(uint4*)&As[rq + g * 64][q * 8] = av[g];
      *(uint4*)&Bs[rq + g * 64][q * 8] = bv[g];
    }
    __syncthreads();
    s8v af[4], bf_[4];
#pragma unroll
    for (int i = 0; i < 4; ++i) {
      af[i] = *(const s8v*)&As[wi + i * 16 + fr][quad * 8];
      bf_[i] = *(const s8v*)&Bs[wj + i * 16 + fr][quad * 8];
    }
#pragma unroll
    for (int i = 0; i < 4; ++i)
#pragma unroll
      for (int j = 0; j < 4; ++j)
        acc[i][j] =
            __builtin_amdgcn_mfma_f32_16x16x32_bf16(af[i], bf_[j], acc[i][j], 0, 0, 0);
  }
#pragma unroll
  for (int i = 0; i < 4; ++i) {
    int rbase = m0 + wi + i * 16 + quad * 4;
#pragma unroll
    for (int j = 0; j < 4; ++j) {
      int col = n0 + wj + j * 16 + fr;
#pragma unroll
      for (int r = 0; r < 4; ++r) {
        int row = rbase + r;
        if (row < M) C[(size_t)row * Nout + col] = fb(acc[i][j][r]);
      }
    }
  }
  score_epilogue(acc, a_src, a_dst, alo, ahi, m0, n0, wi, wj, quad, fr, M);
}

// ---------- 128x128-tile GEMM, f32 A input + fused scores (layer 1) ----------
__global__ __launch_bounds__(256) void gemm128_f32(
    const float* __restrict__ A, const u16* __restrict__ W,
    u16* __restrict__ C, const float* __restrict__ a_src,
    const float* __restrict__ a_dst, float* __restrict__ alo,
    float* __restrict__ ahi, int M, int Nout, int K) {
  __shared__ u16 As[128][40];
  __shared__ u16 Bs[128][40];
  const int t = threadIdx.x;
  const int m0 = blockIdx.y * 128, n0 = blockIdx.x * 128;
  const int rq = t >> 2, q = t & 3;
  const int w = t >> 6, lane = t & 63;
  const int wi = (w & 1) * 64, wj = (w >> 1) * 64;
  const int quad = lane >> 4, fr = lane & 15;

  f4v acc[4][4] = {};
  for (int k0 = 0; k0 < K; k0 += 32) {
    uint4 av[2], bv[2];
#pragma unroll
    for (int g = 0; g < 2; ++g) {
      int r = rq + g * 64;
      int m = m0 + r;
      if (m < M) {
        float4 f0 = *(const float4*)&A[(size_t)m * K + k0 + q * 8];
        float4 f1 = *(const float4*)&A[(size_t)m * K + k0 + q * 8 + 4];
        av[g].x = (unsigned)fb(f0.x) | ((unsigned)fb(f0.y) << 16);
        av[g].y = (unsigned)fb(f0.z) | ((unsigned)fb(f0.w) << 16);
        av[g].z = (unsigned)fb(f1.x) | ((unsigned)fb(f1.y) << 16);
        av[g].w = (unsigned)fb(f1.z) | ((unsigned)fb(f1.w) << 16);
      } else {
        av[g] = make_uint4(0, 0, 0, 0);
      }
      bv[g] = *(const uint4*)&W[(size_t)(n0 + r) * K + k0 + q * 8];
    }
    __syncthreads();
#pragma unroll
    for (int g = 0; g < 2; ++g) {
      *(uint4*)&As[rq + g * 64][q * 8] = av[g];
      *(uint4*)&Bs[rq + g * 64][q * 8] = bv[g];
    }
    __syncthreads();
    s8v af[4], bf_[4];
#pragma unroll
    for (int i = 0; i < 4; ++i) {
      af[i] = *(const s8v*)&As[wi + i * 16 + fr][quad * 8];
      bf_[i] = *(const s8v*)&Bs[wj + i * 16 + fr][quad * 8];
    }
#pragma unroll
    for (int i = 0; i < 4; ++i)
#pragma unroll
      for (int j = 0; j < 4; ++j)
        acc[i][j] =
            __builtin_amdgcn_mfma_f32_16x16x32_bf16(af[i], bf_[j], acc[i][j], 0, 0, 0);
  }
#pragma unroll
  for (int i = 0; i < 4; ++i) {
    int rbase = m0 + wi + i * 16 + quad * 4;
#pragma unroll
    for (int j = 0; j < 4; ++j) {
      int col = n0 + wj + j * 16 + fr;
#pragma unroll
      for (int r = 0; r < 4; ++r) {
        int row = rbase + r;
        if (row < M) C[(size_t)row * Nout + col] = fb(acc[i][j][r]);
      }
    }
  }
  score_epilogue(acc, a_src, a_dst, alo, ahi, m0, n0, wi, wj, quad, fr, M);
}

// ---------- 64x64-tile GEMM + fused H=1 scores (layer 3, Nout=64) ----------
__global__ __launch_bounds__(256) void gemm64_s(
    const u16* __restrict__ A, const u16* __restrict__ W,
    u16* __restrict__ C, const float* __restrict__ a_src,
    const float* __restrict__ a_dst, float* __restrict__ alo,
    float* __restrict__ ahi, int M, int Nout, int K) {
  __shared__ u16 As[64][40];
  __shared__ u16 Bs[64][40];
  __shared__ float sh_s[64][2], sh_d[64][2];
  const int t = threadIdx.x;
  const int m0 = blockIdx.y * 64, n0 = blockIdx.x * 64;
  const int r = t >> 2, c = t & 3;
  const int w = t >> 6, lane = t & 63;
  const int mi = (w & 1) * 32, ni = (w >> 1) * 32;
  const int quad = lane >> 4, fr = lane & 15;

  f4v c00{}, c01{}, c10{}, c11{};
  for (int k0 = 0; k0 < K; k0 += 32) {
    uint4 av = make_uint4(0, 0, 0, 0);
    int m = m0 + r;
    if (m < M) av = *(const uint4*)&A[(size_t)m * K + k0 + c * 8];
    uint4 bv = *(const uint4*)&W[(size_t)(n0 + r) * K + k0 + c * 8];
    __syncthreads();
    *(uint4*)&As[r][c * 8] = av;
    *(uint4*)&Bs[r][c * 8] = bv;
    __syncthreads();
    s8v a0 = *(const s8v*)&As[mi + fr][quad * 8];
    s8v a1 = *(const s8v*)&As[mi + 16 + fr][quad * 8];
    s8v b0 = *(const s8v*)&Bs[ni + fr][quad * 8];
    s8v b1 = *(const s8v*)&Bs[ni + 16 + fr][quad * 8];
    c00 = __builtin_amdgcn_mfma_f32_16x16x32_bf16(a0, b0, c00, 0, 0, 0);
    c01 = __builtin_amdgcn_mfma_f32_16x16x32_bf16(a0, b1, c01, 0, 0, 0);
    c10 = __builtin_amdgcn_mfma_f32_16x16x32_bf16(a1, b0, c10, 0, 0, 0);
    c11 = __builtin_amdgcn_mfma_f32_16x16x32_bf16(a1, b1, c11, 0, 0, 0);
  }
  const int col = n0 + ni + fr;
#pragma unroll
  for (int i = 0; i < 4; ++i) {
    int row = m0 + mi + quad * 4 + i;
    if (row < M) {
      C[(size_t)row * Nout + col] = fb(c00[i]);
      C[(size_t)row * Nout + col + 16] = fb(c01[i]);
    }
    int row2 = row + 16;
    if (row2 < M) {
      C[(size_t)row2 * Nout + col] = fb(c10[i]);
      C[(size_t)row2 * Nout + col + 16] = fb(c11[i]);
    }
  }
  // fused H=1 scores: wave covers rows [mi,mi+32), cols [ni,ni+32)
  const float as_lo = a_src[ni + fr], as_hi = a_src[ni + 16 + fr];
  const float ad_lo = a_dst[ni + fr], ad_hi = a_dst[ni + 16 + fr];
#pragma unroll
  for (int i = 0; i < 4; ++i) {
    float s0 = c00[i] * as_lo + c01[i] * as_hi;
    float d0 = c00[i] * ad_lo + c01[i] * ad_hi;
    float s1 = c10[i] * as_lo + c11[i] * as_hi;
    float d1 = c10[i] * ad_lo + c11[i] * ad_hi;
#pragma unroll
    for (int off = 8; off; off >>= 1) {
      s0 += __shfl_xor(s0, off, 64);
      d0 += __shfl_xor(d0, off, 64);
      s1 += __shfl_xor(s1, off, 64);
      d1 += __shfl_xor(d1, off, 64);
    }
    if (fr == 0) {
      sh_s[mi + quad * 4 + i][ni >> 5] = s0;
      sh_d[mi + quad * 4 + i][ni >> 5] = d0;
      sh_s[mi + 16 + quad * 4 + i][ni >> 5] = s1;
      sh_d[mi + 16 + quad * 4 + i][ni >> 5] = d1;
    }
  }
  __syncthreads();
  if (t < 64) {
    int row = m0 + t;
    if (row < M) {
      alo[row] = sh_s[t][0] + sh_s[t][1];
      ahi[row] = sh_d[t][0] + sh_d[t][1];
    }
  }
}

// ---------- aggregation H=4: single-pass softmax, no cross-lane ops ----
__global__ __launch_bounds__(64) void agg4(
    const int* __restrict__ rowstart, const int* __restrict__ esrc,
    const u16* __restrict__ hbuf, const float* __restrict__ alo,
    const float* __restrict__ ahi, const float* __restrict__ bias,
    u16* __restrict__ feat) {
  const int d = blockIdx.x;
  const int lane = threadIdx.x;
  const int head = lane >> 4;
  const int c = lane * 4;
  const int s0 = rowstart[d], s1 = rowstart[d + 1];
  const float ah = ahi[d * 4 + head];

  float l = 0.f, o0 = 0.f, o1 = 0.f, o2 = 0.f, o3 = 0.f;
  for (int j = s0; j < s1; j += 8) {
    int ss[8];
    float wq[8];
#pragma unroll
    for (int q = 0; q < 8; ++q) {
      int jj = j + q;
      int sv = esrc[jj < EP_EDGES ? jj : EP_EDGES - 1];
      ss[q] = (jj < s1) ? sv : d;
    }
#pragma unroll
    for (int q = 0; q < 8; ++q) {
      float e = alo[ss[q] * 4 + head] + ah;
      e = e > 0.f ? e : 0.2f * e;
      wq[q] = (j + q < s1) ? __expf(e) : 0.f;
    }
    uint2 hv[8];
#pragma unroll
    for (int q = 0; q < 8; ++q)
      hv[q] = *(const uint2*)&hbuf[(size_t)ss[q] * 256 + c];
#pragma unroll
    for (int q = 0; q < 8; ++q) {
      l += wq[q];
      o0 += wq[q] * bfl(hv[q].x);
      o1 += wq[q] * bfh(hv[q].x);
      o2 += wq[q] * bfl(hv[q].y);
      o3 += wq[q] * bfh(hv[q].y);
    }
  }
  const float inv = 1.f / (l + 1e-16f);
  float4 bv = *(const float4*)&bias[c];
  float v0 = o0 * inv + bv.x, v1 = o1 * inv + bv.y;
  float v2 = o2 * inv + bv.z, v3 = o3 * inv + bv.w;
  v0 = v0 > 0.f ? v0 : __expf(v0) - 1.f;
  v1 = v1 > 0.f ? v1 : __expf(v1) - 1.f;
  v2 = v2 > 0.f ? v2 : __expf(v2) - 1.f;
  v3 = v3 > 0.f ? v3 : __expf(v3) - 1.f;
  uint2 pv;
  pv.x = (unsigned)fb(v0) | ((unsigned)fb(v1) << 16);
  pv.y = (unsigned)fb(v2) | ((unsigned)fb(v3) << 16);
  *(uint2*)&feat[(size_t)d * 256 + c] = pv;
}

// ---------- aggregation H=1: single-pass, precomputed alo/ahi ----------
__global__ __launch_bounds__(64) void agg1(
    const int* __restrict__ rowstart, const int* __restrict__ esrc,
    const u16* __restrict__ hbuf, const float* __restrict__ alo,
    const float* __restrict__ ahi, const float* __restrict__ bias,
    float* __restrict__ feat) {
  const int d = blockIdx.x;
  const int t = threadIdx.x;
  const int s0 = rowstart[d], s1 = rowstart[d + 1];
  const float ah = ahi[d];

  float l = 0.f, o = 0.f;
  for (int j = s0; j < s1; j += 4) {
    int ss[4];
    float wq[4];
#pragma unroll
    for (int q = 0; q < 4; ++q) {
      int jj = j + q;
      int sv = esrc[jj < EP_EDGES ? jj : EP_EDGES - 1];
      ss[q] = (jj < s1) ? sv : d;
    }
#pragma unroll
    for (int q = 0; q < 4; ++q) {
      float e = alo[ss[q]] + ah;
      e = e > 0.f ? e : 0.2f * e;
      wq[q] = (j + q < s1) ? __expf(e) : 0.f;
    }
    u16 hv[4];
#pragma unroll
    for (int q = 0; q < 4; ++q) hv[q] = hbuf[(size_t)ss[q] * 64 + t];
#pragma unroll
    for (int q = 0; q < 4; ++q) {
      l += wq[q];
      o += wq[q] * bff(hv[q]);
    }
  }
  float v = o / (l + 1e-16f) + bias[t];
  feat[(size_t)d * 64 + t] = v > 0.f ? v : __expf(v) - 1.f;
}

// ---------- fused mean-pool + MLP heads: one block per graph ----------
__global__ __launch_bounds__(64) void poolheads(
    const float* __restrict__ feat, const int* __restrict__ batch,
    const float* __restrict__ Wc1, const float* __restrict__ bc1,
    const float* __restrict__ Wc2, const float* __restrict__ bc2,
    const float* __restrict__ Wr1, const float* __restrict__ br1,
    const float* __restrict__ Wr2, const float* __restrict__ br2,
    float* __restrict__ out) {
  const int gi = blockIdx.x, t = threadIdx.x;
  int l = 0, r = N_NODES;
  while (l < r) { int m = (l + r) >> 1; if (batch[m] < gi) l = m + 1; else r = m; }
  const int lo = l;
  r = N_NODES;
  while (l < r) { int m = (l + r) >> 1; if (batch[m] < gi + 1) l = m + 1; else r = m; }
  const int hi = l;

  float acc = 0.f;
  for (int n = lo; n < hi; ++n) acc += feat[(size_t)n * 64 + t];
  float cnt = (float)(hi - lo);
  cnt = cnt < 1.f ? 1.f : cnt;

  __shared__ float g[64];
  g[t] = acc / cnt;
  __syncthreads();
  float hc = bc1[t], hr = br1[t];
#pragma unroll 8
  for (int c = 0; c < 64; ++c) {
    float gv = g[c];
    hc += gv * Wc1[t * 64 + c];
    hr += gv * Wr1[t * 64 + c];
  }
  hc = fmaxf(hc, 0.f) * Wc2[t];
  hr = fmaxf(hr, 0.f) * Wr2[t];
#pragma unroll
  for (int off = 32; off; off >>= 1) {
    hc += __shfl_down(hc, off, 64);
    hr += __shfl_down(hr, off, 64);
  }
  if (t == 0) {
    out[gi] = hc + bc2[0];
    out[N_GRAPHS + gi] = hr + br2[0];
  }
}

extern "C" void kernel_launch(void* const* d_in, const int* in_sizes, int n_in,
                              void* d_out, int out_size, void* d_ws,
                              size_t ws_size, hipStream_t stream) {
  const float* x   = (const float*)d_in[0];
  const int* ei    = (const int*)d_in[1];
  const int* batch = (const int*)d_in[2];
  const float* W1  = (const float*)d_in[3];
  const float* as1 = (const float*)d_in[4];
  const float* ad1 = (const float*)d_in[5];
  const float* b1  = (const float*)d_in[6];
  const float* W2  = (const float*)d_in[7];
  const float* as2 = (const float*)d_in[8];
  const float* ad2 = (const float*)d_in[9];
  const float* b2  = (const float*)d_in[10];
  const float* W3  = (const float*)d_in[11];
  const float* as3 = (const float*)d_in[12];
  const float* ad3 = (const float*)d_in[13];
  const float* b3  = (const float*)d_in[14];
  const float* Wc1 = (const float*)d_in[15];
  const float* bc1 = (const float*)d_in[16];
  const float* Wc2 = (const float*)d_in[17];
  const float* bc2 = (const float*)d_in[18];
  const float* Wr1 = (const float*)d_in[19];
  const float* br1 = (const float*)d_in[20];
  const float* Wr2 = (const float*)d_in[21];
  const float* br2 = (const float*)d_in[22];
  float* out = (float*)d_out;

  // ---- workspace layout ----
  float* ws = (float*)d_ws;
  u16* h_buf = (u16*)ws;
  float* p = ws + (size_t)N_NODES * 128;
  u16* featb = (u16*)p;
  p += (size_t)N_NODES * 128;
  u16* W1b = (u16*)p; p += 16384;
  u16* W2b = (u16*)p; p += 32768;
  u16* W3b = (u16*)p; p += 8192;
  float* feat3 = p;   p += (size_t)N_NODES * 64;
  float* alo   = p;   p += (size_t)N_NODES * 4;
  float* ahi   = p;   p += (size_t)N_NODES * 4;
  int* rowstart = (int*)p; p += (N_NODES + 4);
  int* esrc    = (int*)p;  p += EP_EDGES;
  float* bsc   = p;
  int* deg  = (int*)alo;                // [N] (clobbered before alo is written)
  int* fill = (int*)alo + N_NODES;      // [N] adjacent -> single memset
  int* bsum = (int*)bsc;                // [256]
  int* boff = (int*)bsc + 256;          // [256]

  // ---- CSR build (separate oversubscribed kernels) ----
  hipMemsetAsync(deg, 0, (size_t)2 * N_NODES * 4, stream);  // deg + fill
  const int eblk = (EP_EDGES + 255) / 256;
  k_hist<<<eblk, 256, 0, stream>>>(ei, deg);
  k_scan_local<<<NBLK_SCAN, 256, 0, stream>>>(deg, rowstart, bsum);
  k_scan_bsum<<<1, 256, 0, stream>>>(bsum, boff);
  k_scan_add<<<(N_NODES + 256) / 256, 256, 0, stream>>>(rowstart, boff);
  k_scatter<<<eblk, 256, 0, stream>>>(ei, rowstart, fill, esrc);

  // ---- weight bf16 conversion ----
  f2bw<<<(W_N3 + 255) / 256, 256, 0, stream>>>(W1, W2, W3, W1b, W2b, W3b);

  const int MB128 = (N_NODES + 127) / 128;
  const int MB64 = (N_NODES + 63) / 64;
  // ---- layer 1 (f32 x input; scores fused) ----
  gemm128_f32<<<dim3(2, MB128), 256, 0, stream>>>(x, W1b, h_buf, as1, ad1, alo,
                                                  ahi, N_NODES, 256, 128);
  agg4<<<N_NODES, 64, 0, stream>>>(rowstart, esrc, h_buf, alo, ahi, b1, featb);
  // ---- layer 2 (scores fused) ----
  gemm128<<<dim3(2, MB128), 256, 0, stream>>>(featb, W2b, h_buf, as2, ad2, alo,
                                              ahi, N_NODES, 256, 256);
  agg4<<<N_NODES, 64, 0, stream>>>(rowstart, esrc, h_buf, alo, ahi, b2, featb);
  // ---- layer 3 (scores fused in gemm64_s epilogue) ----
  gemm64_s<<<dim3(1, MB64), 256, 0, stream>>>(featb, W3b, h_buf, as3, ad3, alo,
                                              ahi, N_NODES, 64, 256);
  agg1<<<N_NODES, 64, 0, stream>>>(rowstart, esrc, h_buf, alo, ahi, b3, feat3);

  // ---- fused mean pool + heads ----
  poolheads<<<N_GRAPHS, 64, 0, stream>>>(feat3, batch, Wc1, bc1, Wc2, bc2, Wr1,
                                         br1, Wr2, br2, out);
}

// Round 13
// 509.324 us; speedup vs baseline: 1.3657x; 1.0617x over previous
//
#include <hip/hip_runtime.h>

#define N_NODES 50000
#define N_EDGES 800000
#define EP_EDGES (N_EDGES + N_NODES)
#define N_GRAPHS 256
#define NBLK_SCAN ((N_NODES + 255) / 256)

typedef unsigned short u16;
typedef __attribute__((ext_vector_type(8))) short s8v;    // 8 x bf16 (4 VGPRs)
typedef __attribute__((ext_vector_type(4))) float f4v;    // mfma accumulator

// ---------- bf16 helpers (RNE) ----------
__device__ __forceinline__ u16 fb(float f) {
  unsigned u = __float_as_uint(f);
  return (u16)((u + 0x7fffu + ((u >> 16) & 1u)) >> 16);
}
__device__ __forceinline__ float bfl(unsigned p) {
  return __uint_as_float(p << 16);
}
__device__ __forceinline__ float bfh(unsigned p) {
  return __uint_as_float(p & 0xffff0000u);
}
__device__ __forceinline__ float bff(u16 s) {
  return __uint_as_float(((unsigned)s) << 16);
}

#define W_N1 32768
#define W_N2 (W_N1 + 65536)
#define W_N3 (W_N2 + 16384)

// ---------- CSR hist + fused weight conversion ----------
__global__ void k_hist(const int* __restrict__ ei, int* __restrict__ deg,
                       const float* __restrict__ w1,
                       const float* __restrict__ w2,
                       const float* __restrict__ w3, u16* __restrict__ w1b,
                       u16* __restrict__ w2b, u16* __restrict__ w3b) {
  int e = blockIdx.x * 256 + threadIdx.x;
  if (e < W_N3) {
    if (e < W_N1) w1b[e] = fb(w1[e]);
    else if (e < W_N2) w2b[e - W_N1] = fb(w2[e - W_N1]);
    else w3b[e - W_N2] = fb(w3[e - W_N2]);
  }
  if (e >= EP_EDGES) return;
  int d = (e < N_EDGES) ? ei[N_EDGES + e] : e - N_EDGES;
  atomicAdd(&deg[d], 1);
}

__global__ void k_scan_local(const int* __restrict__ deg,
                             int* __restrict__ rowstart,
                             int* __restrict__ bsum) {
  __shared__ int sh[256];
  const int tid = threadIdx.x;
  const int i = blockIdx.x * 256 + tid;
  int v = (i < N_NODES) ? deg[i] : 0;
  sh[tid] = v;
  __syncthreads();
  for (int off = 1; off < 256; off <<= 1) {
    int add = (tid >= off) ? sh[tid - off] : 0;
    __syncthreads();
    sh[tid] += add;
    __syncthreads();
  }
  if (i < N_NODES) rowstart[i] = sh[tid] - v;
  if (tid == 255) bsum[blockIdx.x] = sh[255];
}

__global__ void k_scan_bsum(int* __restrict__ bsum, int* __restrict__ boff) {
  __shared__ int sh[256];
  const int tid = threadIdx.x;
  int v = (tid < NBLK_SCAN) ? bsum[tid] : 0;
  sh[tid] = v;
  __syncthreads();
  for (int off = 1; off < 256; off <<= 1) {
    int add = (tid >= off) ? sh[tid - off] : 0;
    __syncthreads();
    sh[tid] += add;
    __syncthreads();
  }
  boff[tid] = sh[tid] - v;
}

__global__ void k_scan_add(int* __restrict__ rowstart,
                           const int* __restrict__ boff) {
  int i = blockIdx.x * 256 + threadIdx.x;
  if (i < N_NODES) rowstart[i] += boff[i >> 8];
  if (i == N_NODES) rowstart[N_NODES] = EP_EDGES;
}

__global__ void k_scatter(const int* __restrict__ ei,
                          const int* __restrict__ rowstart,
                          int* __restrict__ fill, int* __restrict__ esrc) {
  int e = blockIdx.x * 256 + threadIdx.x;
  if (e >= EP_EDGES) return;
  int s, d;
  if (e < N_EDGES) { s = ei[e]; d = ei[N_EDGES + e]; }
  else             { s = d = e - N_EDGES; }
  int pos = rowstart[d] + atomicAdd(&fill[d], 1);
  esrc[pos] = s;
}

// ---------- fused attn-score epilogue (gemm128 family, H=4) ----------
__device__ __forceinline__ void score_epilogue(
    f4v (&acc)[4][4], const float* __restrict__ a_src,
    const float* __restrict__ a_dst, float* __restrict__ alo,
    float* __restrict__ ahi, int m0, int n0, int wi, int wj, int quad, int fr,
    int M) {
  const int head = (n0 + wj) >> 6;
  float as[4], ad[4];
#pragma unroll
  for (int j = 0; j < 4; ++j) {
    int col = n0 + wj + j * 16 + fr;
    as[j] = a_src[col];
    ad[j] = a_dst[col];
  }
#pragma unroll
  for (int i = 0; i < 4; ++i) {
#pragma unroll
    for (int r = 0; r < 4; ++r) {
      float s = 0.f, d = 0.f;
#pragma unroll
      for (int j = 0; j < 4; ++j) {
        s += acc[i][j][r] * as[j];
        d += acc[i][j][r] * ad[j];
      }
#pragma unroll
      for (int off = 8; off; off >>= 1) {
        s += __shfl_xor(s, off, 64);
        d += __shfl_xor(d, off, 64);
      }
      int row = m0 + wi + i * 16 + quad * 4 + r;
      if (fr == 0 && row < M) {
        alo[row * 4 + head] = s;
        ahi[row * 4 + head] = d;
      }
    }
  }
}

// ---------- 128x128-tile bf16 GEMM + fused scores (layer 2) ----------
__global__ __launch_bounds__(256) void gemm128(
    const u16* __restrict__ A, const u16* __restrict__ W,
    u16* __restrict__ C, const float* __restrict__ a_src,
    const float* __restrict__ a_dst, float* __restrict__ alo,
    float* __restrict__ ahi, int M, int Nout, int K) {
  __shared__ u16 As[128][40];
  __shared__ u16 Bs[128][40];
  const int t = threadIdx.x;
  const int m0 = blockIdx.y * 128, n0 = blockIdx.x * 128;
  const int rq = t >> 2, q = t & 3;
  const int w = t >> 6, lane = t & 63;
  const int wi = (w & 1) * 64, wj = (w >> 1) * 64;
  const int quad = lane >> 4, fr = lane & 15;

  f4v acc[4][4] = {};
  for (int k0 = 0; k0 < K; k0 += 32) {
    uint4 av[2], bv[2];
#pragma unroll
    for (int g = 0; g < 2; ++g) {
      int r = rq + g * 64;
      int m = m0 + r;
      av[g] = (m < M) ? *(const uint4*)&A[(size_t)m * K + k0 + q * 8]
                      : make_uint4(0, 0, 0, 0);
      bv[g] = *(const uint4*)&W[(size_t)(n0 + r) * K + k0 + q * 8];
    }
    __syncthreads();
#pragma unroll
    for (int g = 0; g < 2; ++g) {
      *(uint4*)&As[rq + g * 64][q * 8] = av[g];
      *(uint4*)&Bs[rq + g * 64][q * 8] = bv[g];
    }
    __syncthreads();
    s8v af[4], bf_[4];
#pragma unroll
    for (int i = 0; i < 4; ++i) {
      af[i] = *(const s8v*)&As[wi + i * 16 + fr][quad * 8];
      bf_[i] = *(const s8v*)&Bs[wj + i * 16 + fr][quad * 8];
    }
#pragma unroll
    for (int i = 0; i < 4; ++i)
#pragma unroll
      for (int j = 0; j < 4; ++j)
        acc[i][j] =
            __builtin_amdgcn_mfma_f32_16x16x32_bf16(af[i], bf_[j], acc[i][j], 0, 0, 0);
  }
#pragma unroll
  for (int i = 0; i < 4; ++i) {
    int rbase = m0 + wi + i * 16 + quad * 4;
#pragma unroll
    for (int j = 0; j < 4; ++j) {
      int col = n0 + wj + j * 16 + fr;
#pragma unroll
      for (int r = 0; r < 4; ++r) {
        int row = rbase + r;
        if (row < M) C[(size_t)row * Nout + col] = fb(acc[i][j][r]);
      }
    }
  }
  score_epilogue(acc, a_src, a_dst, alo, ahi, m0, n0, wi, wj, quad, fr, M);
}

// ---------- 128x128-tile GEMM, f32 A input + fused scores (layer 1) ----------
__global__ __launch_bounds__(256) void gemm128_f32(
    const float* __restrict__ A, const u16* __restrict__ W,
    u16* __restrict__ C, const float* __restrict__ a_src,
    const float* __restrict__ a_dst, float* __restrict__ alo,
    float* __restrict__ ahi, int M, int Nout, int K) {
  __shared__ u16 As[128][40];
  __shared__ u16 Bs[128][40];
  const int t = threadIdx.x;
  const int m0 = blockIdx.y * 128, n0 = blockIdx.x * 128;
  const int rq = t >> 2, q = t & 3;
  const int w = t >> 6, lane = t & 63;
  const int wi = (w & 1) * 64, wj = (w >> 1) * 64;
  const int quad = lane >> 4, fr = lane & 15;

  f4v acc[4][4] = {};
  for (int k0 = 0; k0 < K; k0 += 32) {
    uint4 av[2], bv[2];
#pragma unroll
    for (int g = 0; g < 2; ++g) {
      int r = rq + g * 64;
      int m = m0 + r;
      if (m < M) {
        float4 f0 = *(const float4*)&A[(size_t)m * K + k0 + q * 8];
        float4 f1 = *(const float4*)&A[(size_t)m * K + k0 + q * 8 + 4];
        av[g].x = (unsigned)fb(f0.x) | ((unsigned)fb(f0.y) << 16);
        av[g].y = (unsigned)fb(f0.z) | ((unsigned)fb(f0.w) << 16);
        av[g].z = (unsigned)fb(f1.x) | ((unsigned)fb(f1.y) << 16);
        av[g].w = (unsigned)fb(f1.z) | ((unsigned)fb(f1.w) << 16);
      } else {
        av[g] = make_uint4(0, 0, 0, 0);
      }
      bv[g] = *(const uint4*)&W[(size_t)(n0 + r) * K + k0 + q * 8];
    }
    __syncthreads();
#pragma unroll
    for (int g = 0; g < 2; ++g) {
      *(uint4*)&As[rq + g * 64][q * 8] = av[g];
      *(uint4*)&Bs[rq + g * 64][q * 8] = bv[g];
    }
    __syncthreads();
    s8v af[4], bf_[4];
#pragma unroll
    for (int i = 0; i < 4; ++i) {
      af[i] = *(const s8v*)&As[wi + i * 16 + fr][quad * 8];
      bf_[i] = *(const s8v*)&Bs[wj + i * 16 + fr][quad * 8];
    }
#pragma unroll
    for (int i = 0; i < 4; ++i)
#pragma unroll
      for (int j = 0; j < 4; ++j)
        acc[i][j] =
            __builtin_amdgcn_mfma_f32_16x16x32_bf16(af[i], bf_[j], acc[i][j], 0, 0, 0);
  }
#pragma unroll
  for (int i = 0; i < 4; ++i) {
    int rbase = m0 + wi + i * 16 + quad * 4;
#pragma unroll
    for (int j = 0; j < 4; ++j) {
      int col = n0 + wj + j * 16 + fr;
#pragma unroll
      for (int r = 0; r < 4; ++r) {
        int row = rbase + r;
        if (row < M) C[(size_t)row * Nout + col] = fb(acc[i][j][r]);
      }
    }
  }
  score_epilogue(acc, a_src, a_dst, alo, ahi, m0, n0, wi, wj, quad, fr, M);
}

// ---------- 64x64-tile GEMM + fused H=1 scores (layer 3, Nout=64) ----------
__global__ __launch_bounds__(256) void gemm64_s(
    const u16* __restrict__ A, const u16* __restrict__ W,
    u16* __restrict__ C, const float* __restrict__ a_src,
    const float* __restrict__ a_dst, float* __restrict__ alo,
    float* __restrict__ ahi, int M, int Nout, int K) {
  __shared__ u16 As[64][40];
  __shared__ u16 Bs[64][40];
  __shared__ float sh_s[64][2], sh_d[64][2];
  const int t = threadIdx.x;
  const int m0 = blockIdx.y * 64, n0 = blockIdx.x * 64;
  const int r = t >> 2, c = t & 3;
  const int w = t >> 6, lane = t & 63;
  const int mi = (w & 1) * 32, ni = (w >> 1) * 32;
  const int quad = lane >> 4, fr = lane & 15;

  f4v c00{}, c01{}, c10{}, c11{};
  for (int k0 = 0; k0 < K; k0 += 32) {
    uint4 av = make_uint4(0, 0, 0, 0);
    int m = m0 + r;
    if (m < M) av = *(const uint4*)&A[(size_t)m * K + k0 + c * 8];
    uint4 bv = *(const uint4*)&W[(size_t)(n0 + r) * K + k0 + c * 8];
    __syncthreads();
    *(uint4*)&As[r][c * 8] = av;
    *(uint4*)&Bs[r][c * 8] = bv;
    __syncthreads();
    s8v a0 = *(const s8v*)&As[mi + fr][quad * 8];
    s8v a1 = *(const s8v*)&As[mi + 16 + fr][quad * 8];
    s8v b0 = *(const s8v*)&Bs[ni + fr][quad * 8];
    s8v b1 = *(const s8v*)&Bs[ni + 16 + fr][quad * 8];
    c00 = __builtin_amdgcn_mfma_f32_16x16x32_bf16(a0, b0, c00, 0, 0, 0);
    c01 = __builtin_amdgcn_mfma_f32_16x16x32_bf16(a0, b1, c01, 0, 0, 0);
    c10 = __builtin_amdgcn_mfma_f32_16x16x32_bf16(a1, b0, c10, 0, 0, 0);
    c11 = __builtin_amdgcn_mfma_f32_16x16x32_bf16(a1, b1, c11, 0, 0, 0);
  }
  const int col = n0 + ni + fr;
#pragma unroll
  for (int i = 0; i < 4; ++i) {
    int row = m0 + mi + quad * 4 + i;
    if (row < M) {
      C[(size_t)row * Nout + col] = fb(c00[i]);
      C[(size_t)row * Nout + col + 16] = fb(c01[i]);
    }
    int row2 = row + 16;
    if (row2 < M) {
      C[(size_t)row2 * Nout + col] = fb(c10[i]);
      C[(size_t)row2 * Nout + col + 16] = fb(c11[i]);
    }
  }
  const float as_lo = a_src[ni + fr], as_hi = a_src[ni + 16 + fr];
  const float ad_lo = a_dst[ni + fr], ad_hi = a_dst[ni + 16 + fr];
#pragma unroll
  for (int i = 0; i < 4; ++i) {
    float s0 = c00[i] * as_lo + c01[i] * as_hi;
    float d0 = c00[i] * ad_lo + c01[i] * ad_hi;
    float s1 = c10[i] * as_lo + c11[i] * as_hi;
    float d1 = c10[i] * ad_lo + c11[i] * ad_hi;
#pragma unroll
    for (int off = 8; off; off >>= 1) {
      s0 += __shfl_xor(s0, off, 64);
      d0 += __shfl_xor(d0, off, 64);
      s1 += __shfl_xor(s1, off, 64);
      d1 += __shfl_xor(d1, off, 64);
    }
    if (fr == 0) {
      sh_s[mi + quad * 4 + i][ni >> 5] = s0;
      sh_d[mi + quad * 4 + i][ni >> 5] = d0;
      sh_s[mi + 16 + quad * 4 + i][ni >> 5] = s1;
      sh_d[mi + 16 + quad * 4 + i][ni >> 5] = d1;
    }
  }
  __syncthreads();
  if (t < 64) {
    int row = m0 + t;
    if (row < M) {
      alo[row] = sh_s[t][0] + sh_s[t][1];
      ahi[row] = sh_d[t][0] + sh_d[t][1];
    }
  }
}

// ---------- aggregation H=4: 4 dsts/block, unclamped main + clamped tail ----
__global__ __launch_bounds__(256) void agg4(
    const int* __restrict__ rowstart, const int* __restrict__ esrc,
    const u16* __restrict__ hbuf, const float* __restrict__ alo,
    const float* __restrict__ ahi, const float* __restrict__ bias,
    u16* __restrict__ feat) {
  const int d = blockIdx.x * 4 + (threadIdx.x >> 6);
  const int lane = threadIdx.x & 63;
  const int head = lane >> 4;
  const int c = lane * 4;
  const int s0 = rowstart[d], s1 = rowstart[d + 1];
  const float ah = ahi[d * 4 + head];

  float l = 0.f, o0 = 0.f, o1 = 0.f, o2 = 0.f, o3 = 0.f;
  int j = s0;
  // main: full 8-chunks, no bounds logic
  for (; j + 8 <= s1; j += 8) {
    int ss[8];
    float wq[8];
#pragma unroll
    for (int q = 0; q < 8; ++q) ss[q] = esrc[j + q];
#pragma unroll
    for (int q = 0; q < 8; ++q) {
      float e = alo[ss[q] * 4 + head] + ah;
      e = e > 0.f ? e : 0.2f * e;
      wq[q] = __expf(e);
    }
    uint2 hv[8];
#pragma unroll
    for (int q = 0; q < 8; ++q)
      hv[q] = *(const uint2*)&hbuf[(size_t)ss[q] * 256 + c];
#pragma unroll
    for (int q = 0; q < 8; ++q) {
      l += wq[q];
      o0 += wq[q] * bfl(hv[q].x);
      o1 += wq[q] * bfh(hv[q].x);
      o2 += wq[q] * bfl(hv[q].y);
      o3 += wq[q] * bfh(hv[q].y);
    }
  }
  // tail: one clamped 8-chunk
  if (j < s1) {
    int ss[8];
    float wq[8];
#pragma unroll
    for (int q = 0; q < 8; ++q) {
      int jj = j + q;
      int sv = esrc[jj < EP_EDGES ? jj : EP_EDGES - 1];
      ss[q] = (jj < s1) ? sv : d;
    }
#pragma unroll
    for (int q = 0; q < 8; ++q) {
      float e = alo[ss[q] * 4 + head] + ah;
      e = e > 0.f ? e : 0.2f * e;
      wq[q] = (j + q < s1) ? __expf(e) : 0.f;
    }
    uint2 hv[8];
#pragma unroll
    for (int q = 0; q < 8; ++q)
      hv[q] = *(const uint2*)&hbuf[(size_t)ss[q] * 256 + c];
#pragma unroll
    for (int q = 0; q < 8; ++q) {
      l += wq[q];
      o0 += wq[q] * bfl(hv[q].x);
      o1 += wq[q] * bfh(hv[q].x);
      o2 += wq[q] * bfl(hv[q].y);
      o3 += wq[q] * bfh(hv[q].y);
    }
  }
  const float inv = 1.f / (l + 1e-16f);
  float4 bv = *(const float4*)&bias[c];
  float v0 = o0 * inv + bv.x, v1 = o1 * inv + bv.y;
  float v2 = o2 * inv + bv.z, v3 = o3 * inv + bv.w;
  v0 = v0 > 0.f ? v0 : __expf(v0) - 1.f;
  v1 = v1 > 0.f ? v1 : __expf(v1) - 1.f;
  v2 = v2 > 0.f ? v2 : __expf(v2) - 1.f;
  v3 = v3 > 0.f ? v3 : __expf(v3) - 1.f;
  uint2 pv;
  pv.x = (unsigned)fb(v0) | ((unsigned)fb(v1) << 16);
  pv.y = (unsigned)fb(v2) | ((unsigned)fb(v3) << 16);
  *(uint2*)&feat[(size_t)d * 256 + c] = pv;
}

// ---------- aggregation H=1: 4 dsts/block, unclamped main + clamped tail ----
__global__ __launch_bounds__(256) void agg1(
    const int* __restrict__ rowstart, const int* __restrict__ esrc,
    const u16* __restrict__ hbuf, const float* __restrict__ alo,
    const float* __restrict__ ahi, const float* __restrict__ bias,
    float* __restrict__ feat) {
  const int d = blockIdx.x * 4 + (threadIdx.x >> 6);
  const int t = threadIdx.x & 63;
  const int s0 = rowstart[d], s1 = rowstart[d + 1];
  const float ah = ahi[d];

  float l = 0.f, o = 0.f;
  int j = s0;
  for (; j + 8 <= s1; j += 8) {
    int ss[8];
    float wq[8];
#pragma unroll
    for (int q = 0; q < 8; ++q) ss[q] = esrc[j + q];
#pragma unroll
    for (int q = 0; q < 8; ++q) {
      float e = alo[ss[q]] + ah;
      e = e > 0.f ? e : 0.2f * e;
      wq[q] = __expf(e);
    }
    u16 hv[8];
#pragma unroll
    for (int q = 0; q < 8; ++q) hv[q] = hbuf[(size_t)ss[q] * 64 + t];
#pragma unroll
    for (int q = 0; q < 8; ++q) {
      l += wq[q];
      o += wq[q] * bff(hv[q]);
    }
  }
  if (j < s1) {
    int ss[8];
    float wq[8];
#pragma unroll
    for (int q = 0; q < 8; ++q) {
      int jj = j + q;
      int sv = esrc[jj < EP_EDGES ? jj : EP_EDGES - 1];
      ss[q] = (jj < s1) ? sv : d;
    }
#pragma unroll
    for (int q = 0; q < 8; ++q) {
      float e = alo[ss[q]] + ah;
      e = e > 0.f ? e : 0.2f * e;
      wq[q] = (j + q < s1) ? __expf(e) : 0.f;
    }
    u16 hv[8];
#pragma unroll
    for (int q = 0; q < 8; ++q) hv[q] = hbuf[(size_t)ss[q] * 64 + t];
#pragma unroll
    for (int q = 0; q < 8; ++q) {
      l += wq[q];
      o += wq[q] * bff(hv[q]);
    }
  }
  float v = o / (l + 1e-16f) + bias[t];
  feat[(size_t)d * 64 + t] = v > 0.f ? v : __expf(v) - 1.f;
}

// ---------- fused mean-pool + MLP heads: one block per graph ----------
__global__ __launch_bounds__(64) void poolheads(
    const float* __restrict__ feat, const int* __restrict__ batch,
    const float* __restrict__ Wc1, const float* __restrict__ bc1,
    const float* __restrict__ Wc2, const float* __restrict__ bc2,
    const float* __restrict__ Wr1, const float* __restrict__ br1,
    const float* __restrict__ Wr2, const float* __restrict__ br2,
    float* __restrict__ out) {
  const int gi = blockIdx.x, t = threadIdx.x;
  int l = 0, r = N_NODES;
  while (l < r) { int m = (l + r) >> 1; if (batch[m] < gi) l = m + 1; else r = m; }
  const int lo = l;
  r = N_NODES;
  while (l < r) { int m = (l + r) >> 1; if (batch[m] < gi + 1) l = m + 1; else r = m; }
  const int hi = l;

  float acc = 0.f;
  for (int n = lo; n < hi; ++n) acc += feat[(size_t)n * 64 + t];
  float cnt = (float)(hi - lo);
  cnt = cnt < 1.f ? 1.f : cnt;

  __shared__ float g[64];
  g[t] = acc / cnt;
  __syncthreads();
  float hc = bc1[t], hr = br1[t];
#pragma unroll 8
  for (int c = 0; c < 64; ++c) {
    float gv = g[c];
    hc += gv * Wc1[t * 64 + c];
    hr += gv * Wr1[t * 64 + c];
  }
  hc = fmaxf(hc, 0.f) * Wc2[t];
  hr = fmaxf(hr, 0.f) * Wr2[t];
#pragma unroll
  for (int off = 32; off; off >>= 1) {
    hc += __shfl_down(hc, off, 64);
    hr += __shfl_down(hr, off, 64);
  }
  if (t == 0) {
    out[gi] = hc + bc2[0];
    out[N_GRAPHS + gi] = hr + br2[0];
  }
}

extern "C" void kernel_launch(void* const* d_in, const int* in_sizes, int n_in,
                              void* d_out, int out_size, void* d_ws,
                              size_t ws_size, hipStream_t stream) {
  const float* x   = (const float*)d_in[0];
  const int* ei    = (const int*)d_in[1];
  const int* batch = (const int*)d_in[2];
  const float* W1  = (const float*)d_in[3];
  const float* as1 = (const float*)d_in[4];
  const float* ad1 = (const float*)d_in[5];
  const float* b1  = (const float*)d_in[6];
  const float* W2  = (const float*)d_in[7];
  const float* as2 = (const float*)d_in[8];
  const float* ad2 = (const float*)d_in[9];
  const float* b2  = (const float*)d_in[10];
  const float* W3  = (const float*)d_in[11];
  const float* as3 = (const float*)d_in[12];
  const float* ad3 = (const float*)d_in[13];
  const float* b3  = (const float*)d_in[14];
  const float* Wc1 = (const float*)d_in[15];
  const float* bc1 = (const float*)d_in[16];
  const float* Wc2 = (const float*)d_in[17];
  const float* bc2 = (const float*)d_in[18];
  const float* Wr1 = (const float*)d_in[19];
  const float* br1 = (const float*)d_in[20];
  const float* Wr2 = (const float*)d_in[21];
  const float* br2 = (const float*)d_in[22];
  float* out = (float*)d_out;

  // ---- workspace layout ----
  float* ws = (float*)d_ws;
  u16* h_buf = (u16*)ws;
  float* p = ws + (size_t)N_NODES * 128;
  u16* featb = (u16*)p;
  p += (size_t)N_NODES * 128;
  u16* W1b = (u16*)p; p += 16384;
  u16* W2b = (u16*)p; p += 32768;
  u16* W3b = (u16*)p; p += 8192;
  float* feat3 = p;   p += (size_t)N_NODES * 64;
  float* alo   = p;   p += (size_t)N_NODES * 4;
  float* ahi   = p;   p += (size_t)N_NODES * 4;
  int* rowstart = (int*)p; p += (N_NODES + 4);
  int* esrc    = (int*)p;  p += EP_EDGES;
  float* bsc   = p;
  int* deg  = (int*)alo;
  int* fill = (int*)alo + N_NODES;
  int* bsum = (int*)bsc;
  int* boff = (int*)bsc + 256;

  // ---- CSR build (hist kernel also converts weights) ----
  hipMemsetAsync(deg, 0, (size_t)2 * N_NODES * 4, stream);  // deg + fill
  const int eblk = (EP_EDGES + 255) / 256;
  k_hist<<<eblk, 256, 0, stream>>>(ei, deg, W1, W2, W3, W1b, W2b, W3b);
  k_scan_local<<<NBLK_SCAN, 256, 0, stream>>>(deg, rowstart, bsum);
  k_scan_bsum<<<1, 256, 0, stream>>>(bsum, boff);
  k_scan_add<<<(N_NODES + 256) / 256, 256, 0, stream>>>(rowstart, boff);
  k_scatter<<<eblk, 256, 0, stream>>>(ei, rowstart, fill, esrc);

  const int MB128 = (N_NODES + 127) / 128;
  const int MB64 = (N_NODES + 63) / 64;
  // ---- layer 1 (f32 x input; scores fused) ----
  gemm128_f32<<<dim3(2, MB128), 256, 0, stream>>>(x, W1b, h_buf, as1, ad1, alo,
                                                  ahi, N_NODES, 256, 128);
  agg4<<<N_NODES / 4, 256, 0, stream>>>(rowstart, esrc, h_buf, alo, ahi, b1,
                                        featb);
  // ---- layer 2 (scores fused) ----
  gemm128<<<dim3(2, MB128), 256, 0, stream>>>(featb, W2b, h_buf, as2, ad2, alo,
                                              ahi, N_NODES, 256, 256);
  agg4<<<N_NODES / 4, 256, 0, stream>>>(rowstart, esrc, h_buf, alo, ahi, b2,
                                        featb);
  // ---- layer 3 (scores fused in gemm64_s epilogue) ----
  gemm64_s<<<dim3(1, MB64), 256, 0, stream>>>(featb, W3b, h_buf, as3, ad3, alo,
                                              ahi, N_NODES, 64, 256);
  agg1<<<N_NODES / 4, 256, 0, stream>>>(rowstart, esrc, h_buf, alo, ahi, b3,
                                        feat3);

  // ---- fused mean pool + heads ----
  poolheads<<<N_GRAPHS, 64, 0, stream>>>(feat3, batch, Wc1, bc1, Wc2, bc2, Wr1,
                                         br1, Wr2, br2, out);
}

// Round 14
// 505.089 us; speedup vs baseline: 1.3771x; 1.0084x over previous
//
#include <hip/hip_runtime.h>

#define N_NODES 50000
#define N_EDGES 800000
#define EP_EDGES (N_EDGES + N_NODES)
#define N_GRAPHS 256
#define NBLK_SCAN ((N_NODES + 255) / 256)

typedef unsigned short u16;
typedef __attribute__((ext_vector_type(8))) short s8v;    // 8 x bf16 (4 VGPRs)
typedef __attribute__((ext_vector_type(4))) float f4v;    // mfma accumulator

// ---------- bf16 helpers (RNE) ----------
__device__ __forceinline__ u16 fb(float f) {
  unsigned u = __float_as_uint(f);
  return (u16)((u + 0x7fffu + ((u >> 16) & 1u)) >> 16);
}
__device__ __forceinline__ float bfl(unsigned p) {
  return __uint_as_float(p << 16);
}
__device__ __forceinline__ float bfh(unsigned p) {
  return __uint_as_float(p & 0xffff0000u);
}
__device__ __forceinline__ float bff(u16 s) {
  return __uint_as_float(((unsigned)s) << 16);
}

#define W_N1 32768
#define W_N2 (W_N1 + 65536)
#define W_N3 (W_N2 + 16384)

// ---------- CSR hist + fused weight conversion ----------
__global__ void k_hist(const int* __restrict__ ei, int* __restrict__ deg,
                       const float* __restrict__ w1,
                       const float* __restrict__ w2,
                       const float* __restrict__ w3, u16* __restrict__ w1b,
                       u16* __restrict__ w2b, u16* __restrict__ w3b) {
  int e = blockIdx.x * 256 + threadIdx.x;
  if (e < W_N3) {
    if (e < W_N1) w1b[e] = fb(w1[e]);
    else if (e < W_N2) w2b[e - W_N1] = fb(w2[e - W_N1]);
    else w3b[e - W_N2] = fb(w3[e - W_N2]);
  }
  if (e >= EP_EDGES) return;
  int d = (e < N_EDGES) ? ei[N_EDGES + e] : e - N_EDGES;
  atomicAdd(&deg[d], 1);
}

__global__ void k_scan_local(const int* __restrict__ deg,
                             int* __restrict__ rowstart,
                             int* __restrict__ bsum) {
  __shared__ int sh[256];
  const int tid = threadIdx.x;
  const int i = blockIdx.x * 256 + tid;
  int v = (i < N_NODES) ? deg[i] : 0;
  sh[tid] = v;
  __syncthreads();
  for (int off = 1; off < 256; off <<= 1) {
    int add = (tid >= off) ? sh[tid - off] : 0;
    __syncthreads();
    sh[tid] += add;
    __syncthreads();
  }
  if (i < N_NODES) rowstart[i] = sh[tid] - v;
  if (tid == 255) bsum[blockIdx.x] = sh[255];
}

__global__ void k_scan_bsum(int* __restrict__ bsum, int* __restrict__ boff) {
  __shared__ int sh[256];
  const int tid = threadIdx.x;
  int v = (tid < NBLK_SCAN) ? bsum[tid] : 0;
  sh[tid] = v;
  __syncthreads();
  for (int off = 1; off < 256; off <<= 1) {
    int add = (tid >= off) ? sh[tid - off] : 0;
    __syncthreads();
    sh[tid] += add;
    __syncthreads();
  }
  boff[tid] = sh[tid] - v;
}

__global__ void k_scan_add(int* __restrict__ rowstart,
                           const int* __restrict__ boff) {
  int i = blockIdx.x * 256 + threadIdx.x;
  if (i < N_NODES) rowstart[i] += boff[i >> 8];
  if (i == N_NODES) rowstart[N_NODES] = EP_EDGES;
}

__global__ void k_scatter(const int* __restrict__ ei,
                          const int* __restrict__ rowstart,
                          int* __restrict__ fill, int* __restrict__ esrc) {
  int e = blockIdx.x * 256 + threadIdx.x;
  if (e >= EP_EDGES) return;
  int s, d;
  if (e < N_EDGES) { s = ei[e]; d = ei[N_EDGES + e]; }
  else             { s = d = e - N_EDGES; }
  int pos = rowstart[d] + atomicAdd(&fill[d], 1);
  esrc[pos] = s;
}

// ---------- fused attn-score epilogue (gemm128 family, H=4) ----------
__device__ __forceinline__ void score_epilogue(
    f4v (&acc)[4][4], const float* __restrict__ a_src,
    const float* __restrict__ a_dst, float* __restrict__ alo,
    float* __restrict__ ahi, int m0, int n0, int wi, int wj, int quad, int fr,
    int M) {
  const int head = (n0 + wj) >> 6;
  float as[4], ad[4];
#pragma unroll
  for (int j = 0; j < 4; ++j) {
    int col = n0 + wj + j * 16 + fr;
    as[j] = a_src[col];
    ad[j] = a_dst[col];
  }
#pragma unroll
  for (int i = 0; i < 4; ++i) {
#pragma unroll
    for (int r = 0; r < 4; ++r) {
      float s = 0.f, d = 0.f;
#pragma unroll
      for (int j = 0; j < 4; ++j) {
        s += acc[i][j][r] * as[j];
        d += acc[i][j][r] * ad[j];
      }
#pragma unroll
      for (int off = 8; off; off >>= 1) {
        s += __shfl_xor(s, off, 64);
        d += __shfl_xor(d, off, 64);
      }
      int row = m0 + wi + i * 16 + quad * 4 + r;
      if (fr == 0 && row < M) {
        alo[row * 4 + head] = s;
        ahi[row * 4 + head] = d;
      }
    }
  }
}

// ---------- 128x128-tile bf16 GEMM + fused scores (layer 2) ----------
__global__ __launch_bounds__(256) void gemm128(
    const u16* __restrict__ A, const u16* __restrict__ W,
    u16* __restrict__ C, const float* __restrict__ a_src,
    const float* __restrict__ a_dst, float* __restrict__ alo,
    float* __restrict__ ahi, int M, int Nout, int K) {
  __shared__ u16 As[128][40];
  __shared__ u16 Bs[128][40];
  const int t = threadIdx.x;
  const int m0 = blockIdx.y * 128, n0 = blockIdx.x * 128;
  const int rq = t >> 2, q = t & 3;
  const int w = t >> 6, lane = t & 63;
  const int wi = (w & 1) * 64, wj = (w >> 1) * 64;
  const int quad = lane >> 4, fr = lane & 15;

  f4v acc[4][4] = {};
  for (int k0 = 0; k0 < K; k0 += 32) {
    uint4 av[2], bv[2];
#pragma unroll
    for (int g = 0; g < 2; ++g) {
      int r = rq + g * 64;
      int m = m0 + r;
      av[g] = (m < M) ? *(const uint4*)&A[(size_t)m * K + k0 + q * 8]
                      : make_uint4(0, 0, 0, 0);
      bv[g] = *(const uint4*)&W[(size_t)(n0 + r) * K + k0 + q * 8];
    }
    __syncthreads();
#pragma unroll
    for (int g = 0; g < 2; ++g) {
      *(uint4*)&As[rq + g * 64][q * 8] = av[g];
      *(uint4*)&Bs[rq + g * 64][q * 8] = bv[g];
    }
    __syncthreads();
    s8v af[4], bf_[4];
#pragma unroll
    for (int i = 0; i < 4; ++i) {
      af[i] = *(const s8v*)&As[wi + i * 16 + fr][quad * 8];
      bf_[i] = *(const s8v*)&Bs[wj + i * 16 + fr][quad * 8];
    }
#pragma unroll
    for (int i = 0; i < 4; ++i)
#pragma unroll
      for (int j = 0; j < 4; ++j)
        acc[i][j] =
            __builtin_amdgcn_mfma_f32_16x16x32_bf16(af[i], bf_[j], acc[i][j], 0, 0, 0);
  }
#pragma unroll
  for (int i = 0; i < 4; ++i) {
    int rbase = m0 + wi + i * 16 + quad * 4;
#pragma unroll
    for (int j = 0; j < 4; ++j) {
      int col = n0 + wj + j * 16 + fr;
#pragma unroll
      for (int r = 0; r < 4; ++r) {
        int row = rbase + r;
        if (row < M) C[(size_t)row * Nout + col] = fb(acc[i][j][r]);
      }
    }
  }
  score_epilogue(acc, a_src, a_dst, alo, ahi, m0, n0, wi, wj, quad, fr, M);
}

// ---------- 128x128-tile GEMM, f32 A input + fused scores (layer 1) ----------
__global__ __launch_bounds__(256) void gemm128_f32(
    const float* __restrict__ A, const u16* __restrict__ W,
    u16* __restrict__ C, const float* __restrict__ a_src,
    const float* __restrict__ a_dst, float* __restrict__ alo,
    float* __restrict__ ahi, int M, int Nout, int K) {
  __shared__ u16 As[128][40];
  __shared__ u16 Bs[128][40];
  const int t = threadIdx.x;
  const int m0 = blockIdx.y * 128, n0 = blockIdx.x * 128;
  const int rq = t >> 2, q = t & 3;
  const int w = t >> 6, lane = t & 63;
  const int wi = (w & 1) * 64, wj = (w >> 1) * 64;
  const int quad = lane >> 4, fr = lane & 15;

  f4v acc[4][4] = {};
  for (int k0 = 0; k0 < K; k0 += 32) {
    uint4 av[2], bv[2];
#pragma unroll
    for (int g = 0; g < 2; ++g) {
      int r = rq + g * 64;
      int m = m0 + r;
      if (m < M) {
        float4 f0 = *(const float4*)&A[(size_t)m * K + k0 + q * 8];
        float4 f1 = *(const float4*)&A[(size_t)m * K + k0 + q * 8 + 4];
        av[g].x = (unsigned)fb(f0.x) | ((unsigned)fb(f0.y) << 16);
        av[g].y = (unsigned)fb(f0.z) | ((unsigned)fb(f0.w) << 16);
        av[g].z = (unsigned)fb(f1.x) | ((unsigned)fb(f1.y) << 16);
        av[g].w = (unsigned)fb(f1.z) | ((unsigned)fb(f1.w) << 16);
      } else {
        av[g] = make_uint4(0, 0, 0, 0);
      }
      bv[g] = *(const uint4*)&W[(size_t)(n0 + r) * K + k0 + q * 8];
    }
    __syncthreads();
#pragma unroll
    for (int g = 0; g < 2; ++g) {
      *(uint4*)&As[rq + g * 64][q * 8] = av[g];
      *(uint4*)&Bs[rq + g * 64][q * 8] = bv[g];
    }
    __syncthreads();
    s8v af[4], bf_[4];
#pragma unroll
    for (int i = 0; i < 4; ++i) {
      af[i] = *(const s8v*)&As[wi + i * 16 + fr][quad * 8];
      bf_[i] = *(const s8v*)&Bs[wj + i * 16 + fr][quad * 8];
    }
#pragma unroll
    for (int i = 0; i < 4; ++i)
#pragma unroll
      for (int j = 0; j < 4; ++j)
        acc[i][j] =
            __builtin_amdgcn_mfma_f32_16x16x32_bf16(af[i], bf_[j], acc[i][j], 0, 0, 0);
  }
#pragma unroll
  for (int i = 0; i < 4; ++i) {
    int rbase = m0 + wi + i * 16 + quad * 4;
#pragma unroll
    for (int j = 0; j < 4; ++j) {
      int col = n0 + wj + j * 16 + fr;
#pragma unroll
      for (int r = 0; r < 4; ++r) {
        int row = rbase + r;
        if (row < M) C[(size_t)row * Nout + col] = fb(acc[i][j][r]);
      }
    }
  }
  score_epilogue(acc, a_src, a_dst, alo, ahi, m0, n0, wi, wj, quad, fr, M);
}

// ---------- 64x64-tile GEMM + fused H=1 scores (layer 3, Nout=64) ----------
__global__ __launch_bounds__(256) void gemm64_s(
    const u16* __restrict__ A, const u16* __restrict__ W,
    u16* __restrict__ C, const float* __restrict__ a_src,
    const float* __restrict__ a_dst, float* __restrict__ alo,
    float* __restrict__ ahi, int M, int Nout, int K) {
  __shared__ u16 As[64][40];
  __shared__ u16 Bs[64][40];
  __shared__ float sh_s[64][2], sh_d[64][2];
  const int t = threadIdx.x;
  const int m0 = blockIdx.y * 64, n0 = blockIdx.x * 64;
  const int r = t >> 2, c = t & 3;
  const int w = t >> 6, lane = t & 63;
  const int mi = (w & 1) * 32, ni = (w >> 1) * 32;
  const int quad = lane >> 4, fr = lane & 15;

  f4v c00{}, c01{}, c10{}, c11{};
  for (int k0 = 0; k0 < K; k0 += 32) {
    uint4 av = make_uint4(0, 0, 0, 0);
    int m = m0 + r;
    if (m < M) av = *(const uint4*)&A[(size_t)m * K + k0 + c * 8];
    uint4 bv = *(const uint4*)&W[(size_t)(n0 + r) * K + k0 + c * 8];
    __syncthreads();
    *(uint4*)&As[r][c * 8] = av;
    *(uint4*)&Bs[r][c * 8] = bv;
    __syncthreads();
    s8v a0 = *(const s8v*)&As[mi + fr][quad * 8];
    s8v a1 = *(const s8v*)&As[mi + 16 + fr][quad * 8];
    s8v b0 = *(const s8v*)&Bs[ni + fr][quad * 8];
    s8v b1 = *(const s8v*)&Bs[ni + 16 + fr][quad * 8];
    c00 = __builtin_amdgcn_mfma_f32_16x16x32_bf16(a0, b0, c00, 0, 0, 0);
    c01 = __builtin_amdgcn_mfma_f32_16x16x32_bf16(a0, b1, c01, 0, 0, 0);
    c10 = __builtin_amdgcn_mfma_f32_16x16x32_bf16(a1, b0, c10, 0, 0, 0);
    c11 = __builtin_amdgcn_mfma_f32_16x16x32_bf16(a1, b1, c11, 0, 0, 0);
  }
  const int col = n0 + ni + fr;
#pragma unroll
  for (int i = 0; i < 4; ++i) {
    int row = m0 + mi + quad * 4 + i;
    if (row < M) {
      C[(size_t)row * Nout + col] = fb(c00[i]);
      C[(size_t)row * Nout + col + 16] = fb(c01[i]);
    }
    int row2 = row + 16;
    if (row2 < M) {
      C[(size_t)row2 * Nout + col] = fb(c10[i]);
      C[(size_t)row2 * Nout + col + 16] = fb(c11[i]);
    }
  }
  const float as_lo = a_src[ni + fr], as_hi = a_src[ni + 16 + fr];
  const float ad_lo = a_dst[ni + fr], ad_hi = a_dst[ni + 16 + fr];
#pragma unroll
  for (int i = 0; i < 4; ++i) {
    float s0 = c00[i] * as_lo + c01[i] * as_hi;
    float d0 = c00[i] * ad_lo + c01[i] * ad_hi;
    float s1 = c10[i] * as_lo + c11[i] * as_hi;
    float d1 = c10[i] * ad_lo + c11[i] * ad_hi;
#pragma unroll
    for (int off = 8; off; off >>= 1) {
      s0 += __shfl_xor(s0, off, 64);
      d0 += __shfl_xor(d0, off, 64);
      s1 += __shfl_xor(s1, off, 64);
      d1 += __shfl_xor(d1, off, 64);
    }
    if (fr == 0) {
      sh_s[mi + quad * 4 + i][ni >> 5] = s0;
      sh_d[mi + quad * 4 + i][ni >> 5] = d0;
      sh_s[mi + 16 + quad * 4 + i][ni >> 5] = s1;
      sh_d[mi + 16 + quad * 4 + i][ni >> 5] = d1;
    }
  }
  __syncthreads();
  if (t < 64) {
    int row = m0 + t;
    if (row < M) {
      alo[row] = sh_s[t][0] + sh_s[t][1];
      ahi[row] = sh_d[t][0] + sh_d[t][1];
    }
  }
}

// ---------- aggregation H=4 v5: 4 dsts/block, 8ch/lane, 2 edges in flight,
// weights computed once (lanes 0-31) + shfl broadcast ----------
__global__ __launch_bounds__(256) void agg4(
    const int* __restrict__ rowstart, const int* __restrict__ esrc,
    const u16* __restrict__ hbuf, const float* __restrict__ alo,
    const float* __restrict__ ahi, const float* __restrict__ bias,
    u16* __restrict__ feat) {
  const int d = blockIdx.x * 4 + (threadIdx.x >> 6);
  const int lane = threadIdx.x & 63;
  const int half = lane >> 5;
  const int li = lane & 31;
  const int ch = li * 8;        // 8 contiguous channels (half-duplicated)
  const int head = li >> 3;     // head of these channels; also weight-compute head
  const int e8 = li & 7;        // edge index this lane's weight covers
  const int s0 = rowstart[d], s1 = rowstart[d + 1];
  const float ah = ahi[d * 4 + head];

  float l = 0.f;
  float o[8] = {};
  int j = s0;
  for (; j + 8 <= s1; j += 8) {
    int ss[8];
#pragma unroll
    for (int q = 0; q < 8; ++q) ss[q] = esrc[j + q];
    float ev = alo[ss[e8] * 4 + head] + ah;
    ev = ev > 0.f ? ev : 0.2f * ev;
    float w = __expf(ev);
#pragma unroll
    for (int tt = 0; tt < 4; ++tt) {
      int q = 2 * tt + half;
      float wq = __shfl(w, (head << 3) | q, 64);
      uint4 hv = *(const uint4*)&hbuf[(size_t)ss[q] * 256 + ch];
      l += wq;
      o[0] += wq * bfl(hv.x);
      o[1] += wq * bfh(hv.x);
      o[2] += wq * bfl(hv.y);
      o[3] += wq * bfh(hv.y);
      o[4] += wq * bfl(hv.z);
      o[5] += wq * bfh(hv.z);
      o[6] += wq * bfl(hv.w);
      o[7] += wq * bfh(hv.w);
    }
  }
  if (j < s1) {
    int ss[8];
#pragma unroll
    for (int q = 0; q < 8; ++q) {
      int jj = j + q;
      int sv = esrc[jj < EP_EDGES ? jj : EP_EDGES - 1];
      ss[q] = (jj < s1) ? sv : d;
    }
    float ev = alo[ss[e8] * 4 + head] + ah;
    ev = ev > 0.f ? ev : 0.2f * ev;
    float w = (j + e8 < s1) ? __expf(ev) : 0.f;
#pragma unroll
    for (int tt = 0; tt < 4; ++tt) {
      int q = 2 * tt + half;
      float wq = __shfl(w, (head << 3) | q, 64);
      uint4 hv = *(const uint4*)&hbuf[(size_t)ss[q] * 256 + ch];
      l += wq;
      o[0] += wq * bfl(hv.x);
      o[1] += wq * bfh(hv.x);
      o[2] += wq * bfl(hv.y);
      o[3] += wq * bfh(hv.y);
      o[4] += wq * bfl(hv.z);
      o[5] += wq * bfh(hv.z);
      o[6] += wq * bfl(hv.w);
      o[7] += wq * bfh(hv.w);
    }
  }
  // cross-half reduce (complementary edge sets)
  l += __shfl_xor(l, 32, 64);
#pragma unroll
  for (int k = 0; k < 8; ++k) o[k] += __shfl_xor(o[k], 32, 64);
  if (half == 0) {
    const float inv = 1.f / (l + 1e-16f);
    float4 b0 = *(const float4*)&bias[ch];
    float4 b1 = *(const float4*)&bias[ch + 4];
    float v[8];
    v[0] = o[0] * inv + b0.x; v[1] = o[1] * inv + b0.y;
    v[2] = o[2] * inv + b0.z; v[3] = o[3] * inv + b0.w;
    v[4] = o[4] * inv + b1.x; v[5] = o[5] * inv + b1.y;
    v[6] = o[6] * inv + b1.z; v[7] = o[7] * inv + b1.w;
#pragma unroll
    for (int k = 0; k < 8; ++k) v[k] = v[k] > 0.f ? v[k] : __expf(v[k]) - 1.f;
    uint4 pv;
    pv.x = (unsigned)fb(v[0]) | ((unsigned)fb(v[1]) << 16);
    pv.y = (unsigned)fb(v[2]) | ((unsigned)fb(v[3]) << 16);
    pv.z = (unsigned)fb(v[4]) | ((unsigned)fb(v[5]) << 16);
    pv.w = (unsigned)fb(v[6]) | ((unsigned)fb(v[7]) << 16);
    *(uint4*)&feat[(size_t)d * 256 + ch] = pv;
  }
}

// ---------- aggregation H=1: 4 dsts/block, weight-broadcast ----------
__global__ __launch_bounds__(256) void agg1(
    const int* __restrict__ rowstart, const int* __restrict__ esrc,
    const u16* __restrict__ hbuf, const float* __restrict__ alo,
    const float* __restrict__ ahi, const float* __restrict__ bias,
    float* __restrict__ feat) {
  const int d = blockIdx.x * 4 + (threadIdx.x >> 6);
  const int t = threadIdx.x & 63;
  const int e8 = t & 7;
  const int s0 = rowstart[d], s1 = rowstart[d + 1];
  const float ah = ahi[d];

  float l = 0.f, o = 0.f;
  int j = s0;
  for (; j + 8 <= s1; j += 8) {
    int ss[8];
#pragma unroll
    for (int q = 0; q < 8; ++q) ss[q] = esrc[j + q];
    float ev = alo[ss[e8]] + ah;
    ev = ev > 0.f ? ev : 0.2f * ev;
    float w = __expf(ev);
    u16 hv[8];
#pragma unroll
    for (int q = 0; q < 8; ++q) hv[q] = hbuf[(size_t)ss[q] * 64 + t];
#pragma unroll
    for (int q = 0; q < 8; ++q) {
      float wq = __shfl(w, (t & ~7) | q, 64);
      l += wq;
      o += wq * bff(hv[q]);
    }
  }
  if (j < s1) {
    int ss[8];
#pragma unroll
    for (int q = 0; q < 8; ++q) {
      int jj = j + q;
      int sv = esrc[jj < EP_EDGES ? jj : EP_EDGES - 1];
      ss[q] = (jj < s1) ? sv : d;
    }
    float ev = alo[ss[e8]] + ah;
    ev = ev > 0.f ? ev : 0.2f * ev;
    float w = (j + e8 < s1) ? __expf(ev) : 0.f;
    u16 hv[8];
#pragma unroll
    for (int q = 0; q < 8; ++q) hv[q] = hbuf[(size_t)ss[q] * 64 + t];
#pragma unroll
    for (int q = 0; q < 8; ++q) {
      float wq = __shfl(w, (t & ~7) | q, 64);
      l += wq;
      o += wq * bff(hv[q]);
    }
  }
  float v = o / (l + 1e-16f) + bias[t];
  feat[(size_t)d * 64 + t] = v > 0.f ? v : __expf(v) - 1.f;
}

// ---------- fused mean-pool + MLP heads: one block per graph ----------
__global__ __launch_bounds__(64) void poolheads(
    const float* __restrict__ feat, const int* __restrict__ batch,
    const float* __restrict__ Wc1, const float* __restrict__ bc1,
    const float* __restrict__ Wc2, const float* __restrict__ bc2,
    const float* __restrict__ Wr1, const float* __restrict__ br1,
    const float* __restrict__ Wr2, const float* __restrict__ br2,
    float* __restrict__ out) {
  const int gi = blockIdx.x, t = threadIdx.x;
  int l = 0, r = N_NODES;
  while (l < r) { int m = (l + r) >> 1; if (batch[m] < gi) l = m + 1; else r = m; }
  const int lo = l;
  r = N_NODES;
  while (l < r) { int m = (l + r) >> 1; if (batch[m] < gi + 1) l = m + 1; else r = m; }
  const int hi = l;

  float acc = 0.f;
  for (int n = lo; n < hi; ++n) acc += feat[(size_t)n * 64 + t];
  float cnt = (float)(hi - lo);
  cnt = cnt < 1.f ? 1.f : cnt;

  __shared__ float g[64];
  g[t] = acc / cnt;
  __syncthreads();
  float hc = bc1[t], hr = br1[t];
#pragma unroll 8
  for (int c = 0; c < 64; ++c) {
    float gv = g[c];
    hc += gv * Wc1[t * 64 + c];
    hr += gv * Wr1[t * 64 + c];
  }
  hc = fmaxf(hc, 0.f) * Wc2[t];
  hr = fmaxf(hr, 0.f) * Wr2[t];
#pragma unroll
  for (int off = 32; off; off >>= 1) {
    hc += __shfl_down(hc, off, 64);
    hr += __shfl_down(hr, off, 64);
  }
  if (t == 0) {
    out[gi] = hc + bc2[0];
    out[N_GRAPHS + gi] = hr + br2[0];
  }
}

extern "C" void kernel_launch(void* const* d_in, const int* in_sizes, int n_in,
                              void* d_out, int out_size, void* d_ws,
                              size_t ws_size, hipStream_t stream) {
  const float* x   = (const float*)d_in[0];
  const int* ei    = (const int*)d_in[1];
  const int* batch = (const int*)d_in[2];
  const float* W1  = (const float*)d_in[3];
  const float* as1 = (const float*)d_in[4];
  const float* ad1 = (const float*)d_in[5];
  const float* b1  = (const float*)d_in[6];
  const float* W2  = (const float*)d_in[7];
  const float* as2 = (const float*)d_in[8];
  const float* ad2 = (const float*)d_in[9];
  const float* b2  = (const float*)d_in[10];
  const float* W3  = (const float*)d_in[11];
  const float* as3 = (const float*)d_in[12];
  const float* ad3 = (const float*)d_in[13];
  const float* b3  = (const float*)d_in[14];
  const float* Wc1 = (const float*)d_in[15];
  const float* bc1 = (const float*)d_in[16];
  const float* Wc2 = (const float*)d_in[17];
  const float* bc2 = (const float*)d_in[18];
  const float* Wr1 = (const float*)d_in[19];
  const float* br1 = (const float*)d_in[20];
  const float* Wr2 = (const float*)d_in[21];
  const float* br2 = (const float*)d_in[22];
  float* out = (float*)d_out;

  // ---- workspace layout ----
  float* ws = (float*)d_ws;
  u16* h_buf = (u16*)ws;
  float* p = ws + (size_t)N_NODES * 128;
  u16* featb = (u16*)p;
  p += (size_t)N_NODES * 128;
  u16* W1b = (u16*)p; p += 16384;
  u16* W2b = (u16*)p; p += 32768;
  u16* W3b = (u16*)p; p += 8192;
  float* feat3 = p;   p += (size_t)N_NODES * 64;
  float* alo   = p;   p += (size_t)N_NODES * 4;
  float* ahi   = p;   p += (size_t)N_NODES * 4;
  int* rowstart = (int*)p; p += (N_NODES + 4);
  int* esrc    = (int*)p;  p += EP_EDGES;
  float* bsc   = p;
  int* deg  = (int*)alo;
  int* fill = (int*)alo + N_NODES;
  int* bsum = (int*)bsc;
  int* boff = (int*)bsc + 256;

  // ---- CSR build (hist kernel also converts weights) ----
  hipMemsetAsync(deg, 0, (size_t)2 * N_NODES * 4, stream);  // deg + fill
  const int eblk = (EP_EDGES + 255) / 256;
  k_hist<<<eblk, 256, 0, stream>>>(ei, deg, W1, W2, W3, W1b, W2b, W3b);
  k_scan_local<<<NBLK_SCAN, 256, 0, stream>>>(deg, rowstart, bsum);
  k_scan_bsum<<<1, 256, 0, stream>>>(bsum, boff);
  k_scan_add<<<(N_NODES + 256) / 256, 256, 0, stream>>>(rowstart, boff);
  k_scatter<<<eblk, 256, 0, stream>>>(ei, rowstart, fill, esrc);

  const int MB128 = (N_NODES + 127) / 128;
  const int MB64 = (N_NODES + 63) / 64;
  // ---- layer 1 (f32 x input; scores fused) ----
  gemm128_f32<<<dim3(2, MB128), 256, 0, stream>>>(x, W1b, h_buf, as1, ad1, alo,
                                                  ahi, N_NODES, 256, 128);
  agg4<<<N_NODES / 4, 256, 0, stream>>>(rowstart, esrc, h_buf, alo, ahi, b1,
                                        featb);
  // ---- layer 2 (scores fused) ----
  gemm128<<<dim3(2, MB128), 256, 0, stream>>>(featb, W2b, h_buf, as2, ad2, alo,
                                              ahi, N_NODES, 256, 256);
  agg4<<<N_NODES / 4, 256, 0, stream>>>(rowstart, esrc, h_buf, alo, ahi, b2,
                                        featb);
  // ---- layer 3 (scores fused in gemm64_s epilogue) ----
  gemm64_s<<<dim3(1, MB64), 256, 0, stream>>>(featb, W3b, h_buf, as3, ad3, alo,
                                              ahi, N_NODES, 64, 256);
  agg1<<<N_NODES / 4, 256, 0, stream>>>(rowstart, esrc, h_buf, alo, ahi, b3,
                                        feat3);

  // ---- fused mean pool + heads ----
  poolheads<<<N_GRAPHS, 64, 0, stream>>>(feat3, batch, Wc1, bc1, Wc2, bc2, Wr1,
                                         br1, Wr2, br2, out);
}